// Round 4
// baseline (1831.707 us; speedup 1.0000x reference)
//
#include <hip/hip_runtime.h>
#include <hip/hip_bf16.h>

typedef __hip_bfloat16 hb;
typedef __bf16 bf16x8 __attribute__((ext_vector_type(8)));
typedef float f32x4 __attribute__((ext_vector_type(4)));

#define N_DEPTH 6
#define N_DIM   512
#define N_HEADS 8
#define N_MLP   2048
#define N_TOK   197
#define N_PATCH 196
#define N_BATCH 64
#define ROWS    (N_BATCH * N_TOK)     /* 12608 */
#define ROWS_PAD 12672                /* 99 * 128 */
#define PROWS   (N_BATCH * N_PATCH)   /* 12544 = 98 * 128 */

// ---------------- workspace layout (bytes) ----------------
#define OFF_WPATCH 0u
#define OFF_WQKV   786432u
#define OFF_WOUT   10223616u
#define OFF_WFC1   13369344u
#define OFF_WFC2   25952256u
#define OFF_XBF    38535168u
#define OFF_CTX    51511296u
#define OFF_BIG    64487424u      /* shared slot: Xp / qkv / h_mlp / out_proj-partial */
#define OFF_XF     116391936u
#define OFF_H1     142344192u     /* fp32 h1 (25.95 MB); vtg (14.68 MB) aliases this */
#define OFF_EXTRA  168296448u     /* fc2 K-split partial (25.95 MB) — ws_size-guarded */
#define WS_NEED_SPLIT (OFF_EXTRA + 25952256u)

// async global->LDS, 16B per lane; LDS dest = wave-uniform base + lane*16
__device__ __forceinline__ void gl2lds(const hb* g, hb* l) {
    __builtin_amdgcn_global_load_lds((const __attribute__((address_space(1))) unsigned int*)g,
                                     (__attribute__((address_space(3))) unsigned int*)l, 16, 0, 0);
}

// ---------------- small utility kernels ----------------

__global__ void cvt_bf16_kernel(const float* __restrict__ in, hb* __restrict__ out, int n) {
    int t = blockIdx.x * 256 + threadIdx.x;
    if (t < n) out[t] = __float2bfloat16(in[t]);
}

__global__ void patchify_kernel(const float* __restrict__ img, hb* __restrict__ Xp) {
    int t = blockIdx.x * 256 + threadIdx.x;
    if (t >= PROWS * 768) return;
    int r = t / 768, j = t % 768;
    int b = r / 196, p = r % 196;
    int ph = p / 14, pw = p % 14;
    int p1 = j / 48, jr = j % 48;
    int p2 = jr / 3, c = jr % 3;
    float v = img[(((size_t)b * 3 + c) * 224 + ph * 16 + p1) * 224 + pw * 16 + p2];
    Xp[t] = __float2bfloat16(v);
}

__global__ void cls_init_kernel(const float* __restrict__ cls, const float* __restrict__ pos,
                                float* __restrict__ xf, hb* __restrict__ xb) {
    int t = blockIdx.x * 256 + threadIdx.x;   // 64*512
    int b = t >> 9, c = t & 511;
    float v = cls[c] + pos[c];
    size_t off = ((size_t)b * N_TOK) * N_DIM + c;
    xf[off] = v;
    xb[off] = __float2bfloat16(v);
}

__global__ void zero_pads_kernel(float* __restrict__ xf, hb* __restrict__ xb, hb* __restrict__ ctx) {
    int t = blockIdx.x * 256 + threadIdx.x;   // 64*512 pad elements
    size_t off = (size_t)ROWS * N_DIM + t;
    xf[off] = 0.f;
    xb[off] = __float2bfloat16(0.f);
    ctx[off] = __float2bfloat16(0.f);
}

__global__ void extract_cls_kernel(const float* __restrict__ xf, float* __restrict__ out) {
    int t = blockIdx.x * 256 + threadIdx.x;   // 64*512
    int b = t >> 9, c = t & 511;
    out[t] = xf[((size_t)b * N_TOK) * N_DIM + c];
}

// ---------------- LayerNorm (fp32 in [+in2] -> fp32 + bf16 out), 1 wave per row ----------------

template <int SUM>
__global__ void __launch_bounds__(256) ln_kernel(const float* __restrict__ in,
                                                 const float* __restrict__ in2,
                                                 const float* __restrict__ w, const float* __restrict__ b,
                                                 float* __restrict__ outf, hb* __restrict__ outb, int rows) {
    int row = blockIdx.x * 4 + (threadIdx.x >> 6);
    int lane = threadIdx.x & 63;
    if (row >= rows) return;
    const float* p = in + (size_t)row * N_DIM;
    float4 v0 = *(const float4*)(p + lane * 8);
    float4 v1 = *(const float4*)(p + lane * 8 + 4);
    float xs[8] = {v0.x, v0.y, v0.z, v0.w, v1.x, v1.y, v1.z, v1.w};
    if constexpr (SUM) {
        const float* p2 = in2 + (size_t)row * N_DIM;
        float4 u0 = *(const float4*)(p2 + lane * 8);
        float4 u1 = *(const float4*)(p2 + lane * 8 + 4);
        xs[0] += u0.x; xs[1] += u0.y; xs[2] += u0.z; xs[3] += u0.w;
        xs[4] += u1.x; xs[5] += u1.y; xs[6] += u1.z; xs[7] += u1.w;
    }
    float s = 0.f, q = 0.f;
#pragma unroll
    for (int j = 0; j < 8; ++j) { s += xs[j]; q += xs[j] * xs[j]; }
#pragma unroll
    for (int o = 32; o > 0; o >>= 1) { s += __shfl_xor(s, o); q += __shfl_xor(q, o); }
    float mean = s * (1.f / 512.f);
    float var = q * (1.f / 512.f) - mean * mean;
    float r = rsqrtf(var + 1e-5f);
    float4 w0 = *(const float4*)(w + lane * 8);
    float4 w1 = *(const float4*)(w + lane * 8 + 4);
    float4 b0 = *(const float4*)(b + lane * 8);
    float4 b1 = *(const float4*)(b + lane * 8 + 4);
    float ws8[8] = {w0.x, w0.y, w0.z, w0.w, w1.x, w1.y, w1.z, w1.w};
    float bs8[8] = {b0.x, b0.y, b0.z, b0.w, b1.x, b1.y, b1.z, b1.w};
    float of[8] __attribute__((aligned(16)));
    hb tb[8] __attribute__((aligned(16)));
#pragma unroll
    for (int j = 0; j < 8; ++j) {
        float y = (xs[j] - mean) * r * ws8[j] + bs8[j];
        of[j] = y;
        tb[j] = __float2bfloat16(y);
    }
    *(float4*)(outf + (size_t)row * N_DIM + lane * 8)     = *(const float4*)&of[0];
    *(float4*)(outf + (size_t)row * N_DIM + lane * 8 + 4) = *(const float4*)&of[4];
    *(float4*)(outb + (size_t)row * N_DIM + lane * 8)     = *(const float4*)&tb[0];
}

// ---------------- GEMM: C[M,N] = A[M,K] @ B[N,K]^T + bias ----------------
// K-loop: m97 structure — global_load_lds width=16, BK=32, 2 barriers.
// Processes K range [blockIdx.z*halfK, (blockIdx.z+1)*halfK); Kstride = full row stride.
// MODE 0: out_bf = acc + bias; V-col blocks also scatter to vtg transposed  (qkv)
// MODE 1: out_bf = gelu_tanh(acc + bias)           (fc1)
// MODE 2: z=0: outf = acc + bias + res ; z=1: outf2 = acc   (out_proj, fc2 split-K)
// MODE 3: patch embed: row remap + pos_emb, writes both f32 and bf16

template <int MODE>
__global__ void __launch_bounds__(256) gemm_bt(const hb* __restrict__ A, const hb* __restrict__ B,
                                               const float* __restrict__ bias, int Kstride, int halfK, int N,
                                               hb* __restrict__ outb, float* __restrict__ outf,
                                               float* __restrict__ outf2,
                                               const float* __restrict__ res, const float* __restrict__ pos,
                                               hb* __restrict__ vtg) {
    __shared__ hb Sm[8192];          // As[128][32] | Bs[128][32]; reused as C-bounce in epilogue
    hb* As = Sm;
    hb* Bs = Sm + 4096;
    const int tid = threadIdx.x;
    const int lane = tid & 63, wid = tid >> 6;
    const int wr = wid >> 1, wc = wid & 1;
    const int quad = lane >> 4, r16 = lane & 15;
    const int m0 = blockIdx.y * 128, n0 = blockIdx.x * 128;
    const int kb = blockIdx.z * halfK;

    const int r0 = lane >> 2, c0 = lane & 3;
    const hb* ga0 = A + (size_t)(m0 + wid * 32 + r0) * Kstride + kb + c0 * 8;
    const hb* ga1 = ga0 + (size_t)16 * Kstride;
    const hb* gb0 = B + (size_t)(n0 + wid * 32 + r0) * Kstride + kb + c0 * 8;
    const hb* gb1 = gb0 + (size_t)16 * Kstride;
    hb* la0 = As + (wid * 32) * 32;       // wave-uniform LDS bases
    hb* la1 = As + (wid * 32 + 16) * 32;
    hb* lb0 = Bs + (wid * 32) * 32;
    hb* lb1 = Bs + (wid * 32 + 16) * 32;

    f32x4 acc[4][4] = {};

    for (int k0 = 0; k0 < halfK; k0 += 32) {
        gl2lds(ga0, la0);
        gl2lds(ga1, la1);
        gl2lds(gb0, lb0);
        gl2lds(gb1, lb1);
        ga0 += 32; ga1 += 32; gb0 += 32; gb1 += 32;
        __syncthreads();
        bf16x8 af[4], bfr[4];
#pragma unroll
        for (int t = 0; t < 4; ++t) {
            af[t]  = *(const bf16x8*)&As[(wr * 64 + t * 16 + r16) * 32 + quad * 8];
            bfr[t] = *(const bf16x8*)&Bs[(wc * 64 + t * 16 + r16) * 32 + quad * 8];
        }
#pragma unroll
        for (int mi = 0; mi < 4; ++mi)
#pragma unroll
            for (int nj = 0; nj < 4; ++nj)
                acc[mi][nj] = __builtin_amdgcn_mfma_f32_16x16x32_bf16(af[mi], bfr[nj], acc[mi][nj], 0, 0, 0);
        __syncthreads();
    }

    if constexpr (MODE == 0 || MODE == 1) {
        const bool isv = (MODE == 0) && (n0 >= 1024);   // uniform per block
        if (!isv) {
            // coalesced epilogue: per-wave 64x32 LDS bounce (wave-private, in-order LDS)
            hb* Cb = Sm + wid * 2048;
#pragma unroll
            for (int p = 0; p < 2; ++p) {
#pragma unroll
                for (int nj2 = 0; nj2 < 2; ++nj2) {
                    int nj = p * 2 + nj2;
                    float bv = bias[n0 + wc * 64 + nj * 16 + r16];
#pragma unroll
                    for (int mi = 0; mi < 4; ++mi)
#pragma unroll
                        for (int e = 0; e < 4; ++e) {
                            float v = acc[mi][nj][e] + bv;
                            if constexpr (MODE == 1) {
                                // tanh-form GELU (max dev vs erf ~3e-4)
                                float y = 0.79788456f * (v + 0.044715f * v * v * v);
                                float t = 1.f - 2.f / (__expf(2.f * y) + 1.f);
                                v = 0.5f * v * (1.f + t);
                            }
                            Cb[(mi * 16 + quad * 4 + e) * 32 + nj2 * 16 + r16] = __float2bfloat16(v);
                        }
                }
#pragma unroll
                for (int it = 0; it < 4; ++it) {
                    int idx = it * 64 + lane;
                    int row = idx >> 2, ch = idx & 3;
                    bf16x8 val = *(const bf16x8*)&Cb[row * 32 + ch * 8];
                    *(bf16x8*)(outb + (size_t)(m0 + wr * 64 + row) * N + n0 + wc * 64 + p * 32 + ch * 8) = val;
                }
            }
        } else {
            // V columns: scalar store + transposed scatter into vtg
#pragma unroll
            for (int mi = 0; mi < 4; ++mi) {
#pragma unroll
                for (int e = 0; e < 4; ++e) {
                    int row = m0 + wr * 64 + mi * 16 + quad * 4 + e;
                    int bb = row / 197;
                    int mm = row - bb * 197;
#pragma unroll
                    for (int nj = 0; nj < 4; ++nj) {
                        int col = n0 + wc * 64 + nj * 16 + r16;
                        float v = acc[mi][nj][e] + bias[col];
                        hb hv = __float2bfloat16(v);
                        outb[(size_t)row * N + col] = hv;
                        if (bb < 64) {
                            int d = col - 1024;
                            vtg[((size_t)(bb * 8 + (d >> 6))) * (64 * 224) + (size_t)(d & 63) * 224 + mm] = hv;
                        }
                    }
                }
            }
        }
    } else if constexpr (MODE == 2) {
        if (blockIdx.z == 0) {
#pragma unroll
            for (int nj = 0; nj < 4; ++nj) {
                int col = n0 + wc * 64 + nj * 16 + r16;
                float bv = bias[col];
#pragma unroll
                for (int mi = 0; mi < 4; ++mi)
#pragma unroll
                    for (int e = 0; e < 4; ++e) {
                        int row = m0 + wr * 64 + mi * 16 + quad * 4 + e;
                        outf[(size_t)row * N + col] = acc[mi][nj][e] + bv + res[(size_t)row * N + col];
                    }
            }
        } else {
#pragma unroll
            for (int nj = 0; nj < 4; ++nj) {
                int col = n0 + wc * 64 + nj * 16 + r16;
#pragma unroll
                for (int mi = 0; mi < 4; ++mi)
#pragma unroll
                    for (int e = 0; e < 4; ++e) {
                        int row = m0 + wr * 64 + mi * 16 + quad * 4 + e;
                        outf2[(size_t)row * N + col] = acc[mi][nj][e];
                    }
            }
        }
    } else {  // MODE 3: patch embed
#pragma unroll
        for (int nj = 0; nj < 4; ++nj) {
            int col = n0 + wc * 64 + nj * 16 + r16;
            float bv = bias[col];
#pragma unroll
            for (int mi = 0; mi < 4; ++mi)
#pragma unroll
                for (int e = 0; e < 4; ++e) {
                    int row = m0 + wr * 64 + mi * 16 + quad * 4 + e;
                    float v = acc[mi][nj][e] + bv;
                    int pidx = row % 196;
                    int row2 = row + row / 196 + 1;
                    v += pos[(size_t)(pidx + 1) * N_DIM + col];
                    outf[(size_t)row2 * N_DIM + col] = v;
                    outb[(size_t)row2 * N_DIM + col] = __float2bfloat16(v);
                }
        }
    }
}

// ---------------- MFMA flash attention: one block per (b, h) ----------------

__global__ void __launch_bounds__(256, 2) attn_kernel(const hb* __restrict__ qkv,
                                                      const hb* __restrict__ vtg,
                                                      hb* __restrict__ ctx) {
    __shared__ hb Ks[224 * 64];      // K  [key][d]     28,672 B
    __shared__ hb Vt[64 * 224];      // V^T[d][key]     28,672 B
    __shared__ hb Pb[4][16 * 40];    // per-wave P bounce
    const int bh = blockIdx.x;
    const int b = bh >> 3, h = bh & 7;
    const int tid = threadIdx.x, lane = tid & 63, wid = tid >> 6;
    const int quad = lane >> 4, r16 = lane & 15;
    const hb* base = qkv + (size_t)(b * N_TOK) * 1536 + h * 64;
    const hb* vbase = vtg + (size_t)bh * (64 * 224);

#pragma unroll
    for (int i = 0; i < 7; ++i) {
        int idx = tid + i * 256;               // 1792 16B chunks
        int m = idx >> 3, c = idx & 7;
        bf16x8 val = {};
        if (m < 197) val = *(const bf16x8*)(base + (size_t)m * 1536 + 512 + c * 8);
        *(bf16x8*)&Ks[m * 64 + c * 8] = val;
    }
#pragma unroll
    for (int i = 0; i < 6; ++i) {
        int idx = tid + i * 256;               // 1536 16B chunks (64 d x 24 chunks)
        int d = idx / 24, mc = idx % 24;
        *(bf16x8*)&Vt[d * 224 + mc * 8] = *(const bf16x8*)(vbase + d * 224 + mc * 8);
    }
    const hb hzero = __float2bfloat16(0.f);
#pragma unroll
    for (int i = 0; i < 8; ++i) {
        int idx = tid + i * 256;               // 2048 scalars (64 d x 32 m)
        int d = idx >> 5, m = 192 + (idx & 31);
        Vt[d * 224 + m] = (m < 197) ? vbase[d * 224 + m] : hzero;
    }

    bf16x8 af[4][2];
#pragma unroll
    for (int mi = 0; mi < 4; ++mi) {
        int q = wid * 64 + mi * 16 + r16;
#pragma unroll
        for (int kc = 0; kc < 2; ++kc)
            af[mi][kc] = *(const bf16x8*)(base + (size_t)q * 1536 + kc * 32 + quad * 8);
    }

    f32x4 o[4][4] = {};
    float mst[4][4], lp[4][4];
#pragma unroll
    for (int mi = 0; mi < 4; ++mi)
#pragma unroll
        for (int e = 0; e < 4; ++e) { mst[mi][e] = -3.0e38f; lp[mi][e] = 0.f; }

    __syncthreads();

    for (int kt = 0; kt < 7; ++kt) {
        bf16x8 bk[2][2], bv[4];
#pragma unroll
        for (int nj = 0; nj < 2; ++nj)
#pragma unroll
            for (int kc = 0; kc < 2; ++kc)
                bk[nj][kc] = *(const bf16x8*)&Ks[(kt * 32 + nj * 16 + r16) * 64 + kc * 32 + quad * 8];
#pragma unroll
        for (int jd = 0; jd < 4; ++jd)
            bv[jd] = *(const bf16x8*)&Vt[(jd * 16 + r16) * 224 + kt * 32 + quad * 8];

        const bool v0 = (kt * 32 + r16) < N_TOK;
        const bool v1 = (kt * 32 + 16 + r16) < N_TOK;

#pragma unroll
        for (int mi = 0; mi < 4; ++mi) {
            f32x4 z = {};
            f32x4 s0v = __builtin_amdgcn_mfma_f32_16x16x32_bf16(af[mi][0], bk[0][0], z, 0, 0, 0);
            s0v = __builtin_amdgcn_mfma_f32_16x16x32_bf16(af[mi][1], bk[0][1], s0v, 0, 0, 0);
            f32x4 s1v = __builtin_amdgcn_mfma_f32_16x16x32_bf16(af[mi][0], bk[1][0], z, 0, 0, 0);
            s1v = __builtin_amdgcn_mfma_f32_16x16x32_bf16(af[mi][1], bk[1][1], s1v, 0, 0, 0);

            float al[4];
#pragma unroll
            for (int e = 0; e < 4; ++e) {
                float s0 = v0 ? s0v[e] * 0.125f : -1e30f;
                float s1 = v1 ? s1v[e] * 0.125f : -1e30f;
                float mx = fmaxf(s0, s1);
#pragma unroll
                for (int off = 1; off < 16; off <<= 1) mx = fmaxf(mx, __shfl_xor(mx, off));
                float mnew = fmaxf(mst[mi][e], mx);
                float alpha = __expf(mst[mi][e] - mnew);
                mst[mi][e] = mnew;
                float p0 = __expf(s0 - mnew);
                float p1 = __expf(s1 - mnew);
                lp[mi][e] = lp[mi][e] * alpha + p0 + p1;
                al[e] = alpha;
                int prow = (quad * 4 + e) * 40;
                Pb[wid][prow + r16]      = __float2bfloat16(p0);
                Pb[wid][prow + 16 + r16] = __float2bfloat16(p1);
            }
#pragma unroll
            for (int jd = 0; jd < 4; ++jd)
#pragma unroll
                for (int e = 0; e < 4; ++e) o[mi][jd][e] *= al[e];
            bf16x8 ap = *(const bf16x8*)&Pb[wid][r16 * 40 + quad * 8];
#pragma unroll
            for (int jd = 0; jd < 4; ++jd)
                o[mi][jd] = __builtin_amdgcn_mfma_f32_16x16x32_bf16(ap, bv[jd], o[mi][jd], 0, 0, 0);
        }
    }

#pragma unroll
    for (int mi = 0; mi < 4; ++mi) {
        float rl[4];
#pragma unroll
        for (int e = 0; e < 4; ++e) {
            float l = lp[mi][e];
#pragma unroll
            for (int off = 1; off < 16; off <<= 1) l += __shfl_xor(l, off);
            rl[e] = 1.f / l;
        }
        int qrow = wid * 64 + mi * 16 + quad * 4;
#pragma unroll
        for (int e = 0; e < 4; ++e) {
            int q = qrow + e;
            if (q < N_TOK) {
                hb* dst = ctx + ((size_t)(b * N_TOK + q)) * N_DIM + h * 64;
#pragma unroll
                for (int jd = 0; jd < 4; ++jd)
                    dst[jd * 16 + r16] = __float2bfloat16(o[mi][jd][e] * rl[e]);
            }
        }
    }
}

// ---------------- launch ----------------

extern "C" void kernel_launch(void* const* d_in, const int* in_sizes, int n_in,
                              void* d_out, int out_size, void* d_ws, size_t ws_size,
                              hipStream_t stream) {
    (void)in_sizes; (void)n_in; (void)out_size;
    const float* img     = (const float*)d_in[0];
    const float* patch_w = (const float*)d_in[1];
    const float* patch_b = (const float*)d_in[2];
    const float* cls_t   = (const float*)d_in[3];
    const float* pos     = (const float*)d_in[4];
    const float* w_qkv   = (const float*)d_in[5];
    const float* b_qkv   = (const float*)d_in[6];
    const float* w_out   = (const float*)d_in[7];
    const float* b_out   = (const float*)d_in[8];
    const float* ln1w    = (const float*)d_in[9];
    const float* ln1b    = (const float*)d_in[10];
    const float* w_fc1   = (const float*)d_in[11];
    const float* b_fc1   = (const float*)d_in[12];
    const float* w_fc2   = (const float*)d_in[13];
    const float* b_fc2   = (const float*)d_in[14];
    const float* ln2w    = (const float*)d_in[15];
    const float* ln2b    = (const float*)d_in[16];

    char* ws = (char*)d_ws;
    hb* wPatch = (hb*)(ws + OFF_WPATCH);
    hb* wQKV   = (hb*)(ws + OFF_WQKV);
    hb* wOut   = (hb*)(ws + OFF_WOUT);
    hb* wFc1   = (hb*)(ws + OFF_WFC1);
    hb* wFc2   = (hb*)(ws + OFF_WFC2);
    hb* x_bf   = (hb*)(ws + OFF_XBF);
    hb* ctx    = (hb*)(ws + OFF_CTX);
    hb* Xp     = (hb*)(ws + OFF_BIG);
    hb* qkv    = (hb*)(ws + OFF_BIG);
    hb* hmid   = (hb*)(ws + OFF_BIG);
    float* bigf = (float*)(ws + OFF_BIG);   // out_proj z=1 partial (qkv dead by then)
    float* x_f = (float*)(ws + OFF_XF);
    float* h1  = (float*)(ws + OFF_H1);
    hb* vtg    = (hb*)(ws + OFF_H1);        // aliases h1; lifetimes disjoint within a layer
    float* extraf = (float*)(ws + OFF_EXTRA);
    const bool fc2_split = (ws_size >= WS_NEED_SPLIT);

    auto cvt = [&](const float* src, hb* dst, int n) {
        cvt_bf16_kernel<<<dim3((n + 255) / 256), dim3(256), 0, stream>>>(src, dst, n);
    };
    cvt(patch_w, wPatch, 512 * 768);
    cvt(w_qkv, wQKV, N_DEPTH * 1536 * 512);
    cvt(w_out, wOut, N_DEPTH * 512 * 512);
    cvt(w_fc1, wFc1, N_DEPTH * 2048 * 512);
    cvt(w_fc2, wFc2, N_DEPTH * 512 * 2048);

    patchify_kernel<<<dim3((PROWS * 768 + 255) / 256), dim3(256), 0, stream>>>(img, Xp);
    gemm_bt<3><<<dim3(4, 98), dim3(256), 0, stream>>>(Xp, wPatch, patch_b, 768, 768, 512,
                                                      x_bf, x_f, nullptr, nullptr, pos, nullptr);
    cls_init_kernel<<<dim3(128), dim3(256), 0, stream>>>(cls_t, pos, x_f, x_bf);
    zero_pads_kernel<<<dim3(128), dim3(256), 0, stream>>>(x_f, x_bf, ctx);

    for (int i = 0; i < N_DEPTH; ++i) {
        gemm_bt<0><<<dim3(12, 99), dim3(256), 0, stream>>>(x_bf, wQKV + (size_t)i * 1536 * 512,
                                                           b_qkv + i * 1536, 512, 512, 1536,
                                                           qkv, nullptr, nullptr, nullptr, nullptr, vtg);
        attn_kernel<<<dim3(512), dim3(256), 0, stream>>>(qkv, vtg, ctx);
        // out_proj: K=512 split into 2x256 via blockIdx.z (z=1 partial -> bigf, qkv region is dead)
        gemm_bt<2><<<dim3(4, 99, 2), dim3(256), 0, stream>>>(ctx, wOut + (size_t)i * 512 * 512,
                                                             b_out + i * 512, 512, 256, 512,
                                                             nullptr, h1, bigf, x_f, nullptr, nullptr);
        ln_kernel<1><<<dim3(3152), dim3(256), 0, stream>>>(h1, bigf, ln1w + i * 512, ln1b + i * 512, x_f, x_bf, ROWS);
        gemm_bt<1><<<dim3(16, 99), dim3(256), 0, stream>>>(x_bf, wFc1 + (size_t)i * 2048 * 512,
                                                           b_fc1 + i * 2048, 512, 512, 2048,
                                                           hmid, nullptr, nullptr, nullptr, nullptr, nullptr);
        if (fc2_split) {
            gemm_bt<2><<<dim3(4, 99, 2), dim3(256), 0, stream>>>(hmid, wFc2 + (size_t)i * 512 * 2048,
                                                                 b_fc2 + i * 512, 2048, 1024, 512,
                                                                 nullptr, h1, extraf, x_f, nullptr, nullptr);
            ln_kernel<1><<<dim3(3152), dim3(256), 0, stream>>>(h1, extraf, ln2w + i * 512, ln2b + i * 512, x_f, x_bf, ROWS);
        } else {
            gemm_bt<2><<<dim3(4, 99, 1), dim3(256), 0, stream>>>(hmid, wFc2 + (size_t)i * 512 * 2048,
                                                                 b_fc2 + i * 512, 2048, 2048, 512,
                                                                 nullptr, h1, nullptr, x_f, nullptr, nullptr);
            ln_kernel<0><<<dim3(3152), dim3(256), 0, stream>>>(h1, nullptr, ln2w + i * 512, ln2b + i * 512, x_f, x_bf, ROWS);
        }
    }

    extract_cls_kernel<<<dim3(128), dim3(256), 0, stream>>>(x_f, (float*)d_out);
}

// Round 5
// 1642.814 us; speedup vs baseline: 1.1150x; 1.1150x over previous
//
#include <hip/hip_runtime.h>
#include <hip/hip_bf16.h>

typedef __hip_bfloat16 hb;
typedef __bf16 bf16x8 __attribute__((ext_vector_type(8)));
typedef float f32x4 __attribute__((ext_vector_type(4)));

#define N_DEPTH 6
#define N_DIM   512
#define N_HEADS 8
#define N_MLP   2048
#define N_TOK   197
#define N_PATCH 196
#define N_BATCH 64
#define ROWS    (N_BATCH * N_TOK)     /* 12608 */
#define ROWS_PAD 12672                /* 99 * 128 */
#define PROWS   (N_BATCH * N_PATCH)   /* 12544 = 98 * 128 */

// ---------------- workspace layout (bytes) ----------------
#define OFF_WPATCH 0u
#define OFF_WQKV   786432u
#define OFF_WOUT   10223616u
#define OFF_WFC1   13369344u
#define OFF_WFC2   25952256u
#define OFF_XBF    38535168u
#define OFF_CTX    51511296u
#define OFF_BIG    64487424u      /* shared slot: Xp / qkv / h_mlp (51,904,512 B) */
#define OFF_XF     116391936u
#define OFF_H1     142344192u     /* fp32 h1 (25.95 MB) */
/* total 168,296,448 B */

// async global->LDS, 16B per lane; LDS dest = wave-uniform base + lane*16
__device__ __forceinline__ void gl2lds(const hb* g, hb* l) {
    __builtin_amdgcn_global_load_lds((const __attribute__((address_space(1))) unsigned int*)g,
                                     (__attribute__((address_space(3))) unsigned int*)l, 16, 0, 0);
}

// ---------------- small utility kernels ----------------

__global__ void cvt_bf16_kernel(const float* __restrict__ in, hb* __restrict__ out, int n) {
    int t = blockIdx.x * 256 + threadIdx.x;
    if (t < n) out[t] = __float2bfloat16(in[t]);
}

__global__ void patchify_kernel(const float* __restrict__ img, hb* __restrict__ Xp) {
    int t = blockIdx.x * 256 + threadIdx.x;
    if (t >= PROWS * 768) return;
    int r = t / 768, j = t % 768;
    int b = r / 196, p = r % 196;
    int ph = p / 14, pw = p % 14;
    int p1 = j / 48, jr = j % 48;
    int p2 = jr / 3, c = jr % 3;
    float v = img[(((size_t)b * 3 + c) * 224 + ph * 16 + p1) * 224 + pw * 16 + p2];
    Xp[t] = __float2bfloat16(v);
}

__global__ void cls_init_kernel(const float* __restrict__ cls, const float* __restrict__ pos,
                                float* __restrict__ xf, hb* __restrict__ xb) {
    int t = blockIdx.x * 256 + threadIdx.x;   // 64*512
    int b = t >> 9, c = t & 511;
    float v = cls[c] + pos[c];
    size_t off = ((size_t)b * N_TOK) * N_DIM + c;
    xf[off] = v;
    xb[off] = __float2bfloat16(v);
}

__global__ void zero_pads_kernel(float* __restrict__ xf, hb* __restrict__ xb, hb* __restrict__ ctx) {
    int t = blockIdx.x * 256 + threadIdx.x;   // 64*512 pad elements
    size_t off = (size_t)ROWS * N_DIM + t;
    xf[off] = 0.f;
    xb[off] = __float2bfloat16(0.f);
    ctx[off] = __float2bfloat16(0.f);
}

__global__ void extract_cls_kernel(const float* __restrict__ xf, float* __restrict__ out) {
    int t = blockIdx.x * 256 + threadIdx.x;   // 64*512
    int b = t >> 9, c = t & 511;
    out[t] = xf[((size_t)b * N_TOK) * N_DIM + c];
}

// ---------------- LayerNorm (fp32 in -> fp32 + bf16 out), 1 wave per row ----------------

__global__ void __launch_bounds__(256) ln_kernel(const float* __restrict__ in,
                                                 const float* __restrict__ w, const float* __restrict__ b,
                                                 float* __restrict__ outf, hb* __restrict__ outb, int rows) {
    int row = blockIdx.x * 4 + (threadIdx.x >> 6);
    int lane = threadIdx.x & 63;
    if (row >= rows) return;
    const float* p = in + (size_t)row * N_DIM;
    float4 v0 = *(const float4*)(p + lane * 8);
    float4 v1 = *(const float4*)(p + lane * 8 + 4);
    float xs[8] = {v0.x, v0.y, v0.z, v0.w, v1.x, v1.y, v1.z, v1.w};
    float s = 0.f, q = 0.f;
#pragma unroll
    for (int j = 0; j < 8; ++j) { s += xs[j]; q += xs[j] * xs[j]; }
#pragma unroll
    for (int o = 32; o > 0; o >>= 1) { s += __shfl_xor(s, o); q += __shfl_xor(q, o); }
    float mean = s * (1.f / 512.f);
    float var = q * (1.f / 512.f) - mean * mean;
    float r = rsqrtf(var + 1e-5f);
    float4 w0 = *(const float4*)(w + lane * 8);
    float4 w1 = *(const float4*)(w + lane * 8 + 4);
    float4 b0 = *(const float4*)(b + lane * 8);
    float4 b1 = *(const float4*)(b + lane * 8 + 4);
    float ws8[8] = {w0.x, w0.y, w0.z, w0.w, w1.x, w1.y, w1.z, w1.w};
    float bs8[8] = {b0.x, b0.y, b0.z, b0.w, b1.x, b1.y, b1.z, b1.w};
    float of[8] __attribute__((aligned(16)));
    hb tb[8] __attribute__((aligned(16)));
#pragma unroll
    for (int j = 0; j < 8; ++j) {
        float y = (xs[j] - mean) * r * ws8[j] + bs8[j];
        of[j] = y;
        tb[j] = __float2bfloat16(y);
    }
    *(float4*)(outf + (size_t)row * N_DIM + lane * 8)     = *(const float4*)&of[0];
    *(float4*)(outf + (size_t)row * N_DIM + lane * 8 + 4) = *(const float4*)&of[4];
    *(float4*)(outb + (size_t)row * N_DIM + lane * 8)     = *(const float4*)&tb[0];
}

// ---------------- GEMM: C[M,N] = A[M,K] @ B[N,K]^T + bias ----------------
// K-loop: global_load_lds width=16 staging, BK=64 (half the barriers vs BK=32).
// MODE 0: out_bf = acc + bias                      (qkv — fully coalesced)
// MODE 1: out_bf = gelu_tanh(acc + bias)           (fc1)
// MODE 2: out_f32 = acc + bias + res_f32           (out_proj, fc2)
// MODE 3: patch embed: row remap + pos_emb, writes both f32 and bf16

template <int MODE>
__global__ void __launch_bounds__(256) gemm_bt(const hb* __restrict__ A, const hb* __restrict__ B,
                                               const float* __restrict__ bias, int K, int N,
                                               hb* __restrict__ outb, float* __restrict__ outf,
                                               const float* __restrict__ res, const float* __restrict__ pos) {
    __shared__ hb Sm[16384];          // As[128][64] | Bs[128][64]; reused as C-bounce in epilogue
    hb* As = Sm;
    hb* Bs = Sm + 8192;
    const int tid = threadIdx.x;
    const int lane = tid & 63, wid = tid >> 6;
    const int wr = wid >> 1, wc = wid & 1;
    const int quad = lane >> 4, r16 = lane & 15;
    const int m0 = blockIdx.y * 128, n0 = blockIdx.x * 128;

    // staging: wave w covers rows [32w, 32w+32) of each tile; one gl2lds = 8 rows
    // (64 lanes x 16B = 1024B). lane -> row 8i + (lane>>3), chunk (lane&7).
    const int r0 = lane >> 3, c0 = lane & 7;
    const hb* ga0 = A + (size_t)(m0 + wid * 32 + r0) * K + c0 * 8;
    const hb* ga1 = ga0 + (size_t)8 * K;
    const hb* ga2 = ga0 + (size_t)16 * K;
    const hb* ga3 = ga0 + (size_t)24 * K;
    const hb* gb0 = B + (size_t)(n0 + wid * 32 + r0) * K + c0 * 8;
    const hb* gb1 = gb0 + (size_t)8 * K;
    const hb* gb2 = gb0 + (size_t)16 * K;
    const hb* gb3 = gb0 + (size_t)24 * K;
    hb* la0 = As + (wid * 32) * 64;       // wave-uniform LDS bases
    hb* la1 = la0 + 8 * 64;
    hb* la2 = la0 + 16 * 64;
    hb* la3 = la0 + 24 * 64;
    hb* lb0 = Bs + (wid * 32) * 64;
    hb* lb1 = lb0 + 8 * 64;
    hb* lb2 = lb0 + 16 * 64;
    hb* lb3 = lb0 + 24 * 64;

    f32x4 acc[4][4] = {};

    for (int k0 = 0; k0 < K; k0 += 64) {
        gl2lds(ga0, la0); gl2lds(ga1, la1); gl2lds(ga2, la2); gl2lds(ga3, la3);
        gl2lds(gb0, lb0); gl2lds(gb1, lb1); gl2lds(gb2, lb2); gl2lds(gb3, lb3);
        ga0 += 64; ga1 += 64; ga2 += 64; ga3 += 64;
        gb0 += 64; gb1 += 64; gb2 += 64; gb3 += 64;
        __syncthreads();
#pragma unroll
        for (int kh = 0; kh < 2; ++kh) {
            bf16x8 af[4], bfr[4];
#pragma unroll
            for (int t = 0; t < 4; ++t) {
                af[t]  = *(const bf16x8*)&As[(wr * 64 + t * 16 + r16) * 64 + kh * 32 + quad * 8];
                bfr[t] = *(const bf16x8*)&Bs[(wc * 64 + t * 16 + r16) * 64 + kh * 32 + quad * 8];
            }
#pragma unroll
            for (int mi = 0; mi < 4; ++mi)
#pragma unroll
                for (int nj = 0; nj < 4; ++nj)
                    acc[mi][nj] = __builtin_amdgcn_mfma_f32_16x16x32_bf16(af[mi], bfr[nj], acc[mi][nj], 0, 0, 0);
        }
        __syncthreads();
    }

    if constexpr (MODE == 0 || MODE == 1) {
        // coalesced epilogue: per-wave 64x32 LDS bounce (wave-private, in-order LDS)
        hb* Cb = Sm + wid * 2048;
#pragma unroll
        for (int p = 0; p < 2; ++p) {
#pragma unroll
            for (int nj2 = 0; nj2 < 2; ++nj2) {
                int nj = p * 2 + nj2;
                float bv = bias[n0 + wc * 64 + nj * 16 + r16];
#pragma unroll
                for (int mi = 0; mi < 4; ++mi)
#pragma unroll
                    for (int e = 0; e < 4; ++e) {
                        float v = acc[mi][nj][e] + bv;
                        if constexpr (MODE == 1) {
                            // tanh-form GELU (max dev vs erf ~3e-4)
                            float y = 0.79788456f * (v + 0.044715f * v * v * v);
                            float t = 1.f - 2.f / (__expf(2.f * y) + 1.f);
                            v = 0.5f * v * (1.f + t);
                        }
                        Cb[(mi * 16 + quad * 4 + e) * 32 + nj2 * 16 + r16] = __float2bfloat16(v);
                    }
            }
#pragma unroll
            for (int it = 0; it < 4; ++it) {
                int idx = it * 64 + lane;
                int row = idx >> 2, ch = idx & 3;
                bf16x8 val = *(const bf16x8*)&Cb[row * 32 + ch * 8];
                *(bf16x8*)(outb + (size_t)(m0 + wr * 64 + row) * N + n0 + wc * 64 + p * 32 + ch * 8) = val;
            }
        }
    } else if constexpr (MODE == 2) {
#pragma unroll
        for (int nj = 0; nj < 4; ++nj) {
            int col = n0 + wc * 64 + nj * 16 + r16;
            float bv = bias[col];
#pragma unroll
            for (int mi = 0; mi < 4; ++mi)
#pragma unroll
                for (int e = 0; e < 4; ++e) {
                    int row = m0 + wr * 64 + mi * 16 + quad * 4 + e;
                    outf[(size_t)row * N + col] = acc[mi][nj][e] + bv + res[(size_t)row * N + col];
                }
        }
    } else {  // MODE 3: patch embed
#pragma unroll
        for (int nj = 0; nj < 4; ++nj) {
            int col = n0 + wc * 64 + nj * 16 + r16;
            float bv = bias[col];
#pragma unroll
            for (int mi = 0; mi < 4; ++mi)
#pragma unroll
                for (int e = 0; e < 4; ++e) {
                    int row = m0 + wr * 64 + mi * 16 + quad * 4 + e;
                    float v = acc[mi][nj][e] + bv;
                    int pidx = row % 196;
                    int row2 = row + row / 196 + 1;
                    v += pos[(size_t)(pidx + 1) * N_DIM + col];
                    outf[(size_t)row2 * N_DIM + col] = v;
                    outb[(size_t)row2 * N_DIM + col] = __float2bfloat16(v);
                }
        }
    }
}

// ---------------- MFMA flash attention: one block per (b, h) ----------------
// qkv row: [q(512)|k(512)|v(512)], head h at cols h*64..h*64+63.
// K and V both staged row-major [m][d] from qkv; PV B-fragment gathered from
// Vs via 8 x ds_read_u16 (2B stride across 16 lanes -> 2-way bank, free).

__global__ void __launch_bounds__(256, 2) attn_kernel(const hb* __restrict__ qkv,
                                                      hb* __restrict__ ctx) {
    __shared__ hb Ks[224 * 64];      // K [key][d]   28,672 B
    __shared__ hb Vs[224 * 64];      // V [key][d]   28,672 B
    __shared__ hb Pb[4][16 * 40];    // per-wave P bounce
    const int bh = blockIdx.x;
    const int b = bh >> 3, h = bh & 7;
    const int tid = threadIdx.x, lane = tid & 63, wid = tid >> 6;
    const int quad = lane >> 4, r16 = lane & 15;
    const hb* base = qkv + (size_t)(b * N_TOK) * 1536 + h * 64;

#pragma unroll
    for (int i = 0; i < 7; ++i) {
        int idx = tid + i * 256;               // 1792 16B chunks
        int m = idx >> 3, c = idx & 7;
        bf16x8 kv = {}, vv = {};
        if (m < 197) {
            kv = *(const bf16x8*)(base + (size_t)m * 1536 + 512 + c * 8);
            vv = *(const bf16x8*)(base + (size_t)m * 1536 + 1024 + c * 8);
        }
        *(bf16x8*)&Ks[m * 64 + c * 8] = kv;
        *(bf16x8*)&Vs[m * 64 + c * 8] = vv;
    }

    // Q fragments: 64 query rows per wave
    bf16x8 af[4][2];
#pragma unroll
    for (int mi = 0; mi < 4; ++mi) {
        int q = wid * 64 + mi * 16 + r16;
#pragma unroll
        for (int kc = 0; kc < 2; ++kc)
            af[mi][kc] = *(const bf16x8*)(base + (size_t)q * 1536 + kc * 32 + quad * 8);
    }

    f32x4 o[4][4] = {};
    float mst[4][4], lp[4][4];
#pragma unroll
    for (int mi = 0; mi < 4; ++mi)
#pragma unroll
        for (int e = 0; e < 4; ++e) { mst[mi][e] = -3.0e38f; lp[mi][e] = 0.f; }

    __syncthreads();

    const __bf16* VsB = (const __bf16*)Vs;
    for (int kt = 0; kt < 7; ++kt) {
        bf16x8 bk[2][2], bv[4];
#pragma unroll
        for (int nj = 0; nj < 2; ++nj)
#pragma unroll
            for (int kc = 0; kc < 2; ++kc)
                bk[nj][kc] = *(const bf16x8*)&Ks[(kt * 32 + nj * 16 + r16) * 64 + kc * 32 + quad * 8];
        // PV B-frag: B[k=m][n=d], lane holds d=jd*16+r16, k=kt*32+quad*8+j
#pragma unroll
        for (int jd = 0; jd < 4; ++jd) {
            bf16x8 t;
#pragma unroll
            for (int j = 0; j < 8; ++j)
                t[j] = VsB[(kt * 32 + quad * 8 + j) * 64 + jd * 16 + r16];
            bv[jd] = t;
        }

        const bool v0 = (kt * 32 + r16) < N_TOK;
        const bool v1 = (kt * 32 + 16 + r16) < N_TOK;

#pragma unroll
        for (int mi = 0; mi < 4; ++mi) {
            f32x4 z = {};
            f32x4 s0v = __builtin_amdgcn_mfma_f32_16x16x32_bf16(af[mi][0], bk[0][0], z, 0, 0, 0);
            s0v = __builtin_amdgcn_mfma_f32_16x16x32_bf16(af[mi][1], bk[0][1], s0v, 0, 0, 0);
            f32x4 s1v = __builtin_amdgcn_mfma_f32_16x16x32_bf16(af[mi][0], bk[1][0], z, 0, 0, 0);
            s1v = __builtin_amdgcn_mfma_f32_16x16x32_bf16(af[mi][1], bk[1][1], s1v, 0, 0, 0);

            float al[4];
#pragma unroll
            for (int e = 0; e < 4; ++e) {
                float s0 = v0 ? s0v[e] * 0.125f : -1e30f;
                float s1 = v1 ? s1v[e] * 0.125f : -1e30f;
                float mx = fmaxf(s0, s1);
#pragma unroll
                for (int off = 1; off < 16; off <<= 1) mx = fmaxf(mx, __shfl_xor(mx, off));
                float mnew = fmaxf(mst[mi][e], mx);
                float alpha = __expf(mst[mi][e] - mnew);
                mst[mi][e] = mnew;
                float p0 = __expf(s0 - mnew);
                float p1 = __expf(s1 - mnew);
                lp[mi][e] = lp[mi][e] * alpha + p0 + p1;
                al[e] = alpha;
                int prow = (quad * 4 + e) * 40;
                Pb[wid][prow + r16]      = __float2bfloat16(p0);
                Pb[wid][prow + 16 + r16] = __float2bfloat16(p1);
            }
#pragma unroll
            for (int jd = 0; jd < 4; ++jd)
#pragma unroll
                for (int e = 0; e < 4; ++e) o[mi][jd][e] *= al[e];
            bf16x8 ap = *(const bf16x8*)&Pb[wid][r16 * 40 + quad * 8];
#pragma unroll
            for (int jd = 0; jd < 4; ++jd)
                o[mi][jd] = __builtin_amdgcn_mfma_f32_16x16x32_bf16(ap, bv[jd], o[mi][jd], 0, 0, 0);
        }
    }

#pragma unroll
    for (int mi = 0; mi < 4; ++mi) {
        float rl[4];
#pragma unroll
        for (int e = 0; e < 4; ++e) {
            float l = lp[mi][e];
#pragma unroll
            for (int off = 1; off < 16; off <<= 1) l += __shfl_xor(l, off);
            rl[e] = 1.f / l;
        }
        int qrow = wid * 64 + mi * 16 + quad * 4;
#pragma unroll
        for (int e = 0; e < 4; ++e) {
            int q = qrow + e;
            if (q < N_TOK) {
                hb* dst = ctx + ((size_t)(b * N_TOK + q)) * N_DIM + h * 64;
#pragma unroll
                for (int jd = 0; jd < 4; ++jd)
                    dst[jd * 16 + r16] = __float2bfloat16(o[mi][jd][e] * rl[e]);
            }
        }
    }
}

// ---------------- launch ----------------

extern "C" void kernel_launch(void* const* d_in, const int* in_sizes, int n_in,
                              void* d_out, int out_size, void* d_ws, size_t ws_size,
                              hipStream_t stream) {
    (void)in_sizes; (void)n_in; (void)out_size; (void)ws_size;
    const float* img     = (const float*)d_in[0];
    const float* patch_w = (const float*)d_in[1];
    const float* patch_b = (const float*)d_in[2];
    const float* cls_t   = (const float*)d_in[3];
    const float* pos     = (const float*)d_in[4];
    const float* w_qkv   = (const float*)d_in[5];
    const float* b_qkv   = (const float*)d_in[6];
    const float* w_out   = (const float*)d_in[7];
    const float* b_out   = (const float*)d_in[8];
    const float* ln1w    = (const float*)d_in[9];
    const float* ln1b    = (const float*)d_in[10];
    const float* w_fc1   = (const float*)d_in[11];
    const float* b_fc1   = (const float*)d_in[12];
    const float* w_fc2   = (const float*)d_in[13];
    const float* b_fc2   = (const float*)d_in[14];
    const float* ln2w    = (const float*)d_in[15];
    const float* ln2b    = (const float*)d_in[16];

    char* ws = (char*)d_ws;
    hb* wPatch = (hb*)(ws + OFF_WPATCH);
    hb* wQKV   = (hb*)(ws + OFF_WQKV);
    hb* wOut   = (hb*)(ws + OFF_WOUT);
    hb* wFc1   = (hb*)(ws + OFF_WFC1);
    hb* wFc2   = (hb*)(ws + OFF_WFC2);
    hb* x_bf   = (hb*)(ws + OFF_XBF);
    hb* ctx    = (hb*)(ws + OFF_CTX);
    hb* Xp     = (hb*)(ws + OFF_BIG);
    hb* qkv    = (hb*)(ws + OFF_BIG);
    hb* hmid   = (hb*)(ws + OFF_BIG);
    float* x_f = (float*)(ws + OFF_XF);
    float* h1  = (float*)(ws + OFF_H1);

    auto cvt = [&](const float* src, hb* dst, int n) {
        cvt_bf16_kernel<<<dim3((n + 255) / 256), dim3(256), 0, stream>>>(src, dst, n);
    };
    cvt(patch_w, wPatch, 512 * 768);
    cvt(w_qkv, wQKV, N_DEPTH * 1536 * 512);
    cvt(w_out, wOut, N_DEPTH * 512 * 512);
    cvt(w_fc1, wFc1, N_DEPTH * 2048 * 512);
    cvt(w_fc2, wFc2, N_DEPTH * 512 * 2048);

    patchify_kernel<<<dim3((PROWS * 768 + 255) / 256), dim3(256), 0, stream>>>(img, Xp);
    gemm_bt<3><<<dim3(4, 98), dim3(256), 0, stream>>>(Xp, wPatch, patch_b, 768, 512,
                                                      x_bf, x_f, nullptr, pos);
    cls_init_kernel<<<dim3(128), dim3(256), 0, stream>>>(cls_t, pos, x_f, x_bf);
    zero_pads_kernel<<<dim3(128), dim3(256), 0, stream>>>(x_f, x_bf, ctx);

    for (int i = 0; i < N_DEPTH; ++i) {
        gemm_bt<0><<<dim3(12, 99), dim3(256), 0, stream>>>(x_bf, wQKV + (size_t)i * 1536 * 512,
                                                           b_qkv + i * 1536, 512, 1536,
                                                           qkv, nullptr, nullptr, nullptr);
        attn_kernel<<<dim3(512), dim3(256), 0, stream>>>(qkv, ctx);
        gemm_bt<2><<<dim3(4, 99), dim3(256), 0, stream>>>(ctx, wOut + (size_t)i * 512 * 512,
                                                          b_out + i * 512, 512, 512,
                                                          nullptr, h1, x_f, nullptr);
        ln_kernel<<<dim3(3152), dim3(256), 0, stream>>>(h1, ln1w + i * 512, ln1b + i * 512, x_f, x_bf, ROWS);
        gemm_bt<1><<<dim3(16, 99), dim3(256), 0, stream>>>(x_bf, wFc1 + (size_t)i * 2048 * 512,
                                                           b_fc1 + i * 2048, 512, 2048,
                                                           hmid, nullptr, nullptr, nullptr);
        gemm_bt<2><<<dim3(4, 99), dim3(256), 0, stream>>>(hmid, wFc2 + (size_t)i * 512 * 2048,
                                                          b_fc2 + i * 512, 2048, 512,
                                                          nullptr, h1, x_f, nullptr);
        ln_kernel<<<dim3(3152), dim3(256), 0, stream>>>(h1, ln2w + i * 512, ln2b + i * 512, x_f, x_bf, ROWS);
    }

    extract_cls_kernel<<<dim3(128), dim3(256), 0, stream>>>(x_f, (float*)d_out);
}

// Round 6
// 1568.260 us; speedup vs baseline: 1.1680x; 1.0475x over previous
//
#include <hip/hip_runtime.h>
#include <hip/hip_bf16.h>

typedef __hip_bfloat16 hb;
typedef __bf16 bf16x8 __attribute__((ext_vector_type(8)));
typedef float f32x4 __attribute__((ext_vector_type(4)));

#define N_DEPTH 6
#define N_DIM   512
#define N_HEADS 8
#define N_MLP   2048
#define N_TOK   197
#define N_PATCH 196
#define N_BATCH 64
#define ROWS    (N_BATCH * N_TOK)     /* 12608 */
#define ROWS_PAD 12672                /* 99 * 128 */
#define PROWS   (N_BATCH * N_PATCH)   /* 12544 = 98 * 128 */

// ---------------- workspace layout (bytes) ----------------
#define OFF_WPATCH 0u
#define OFF_WQKV   786432u
#define OFF_WOUT   10223616u
#define OFF_WFC1   13369344u
#define OFF_WFC2   25952256u
#define OFF_XBF    38535168u
#define OFF_CTX    51511296u
#define OFF_BIG    64487424u      /* shared slot: Xp / qkv / h_mlp (51,904,512 B) */
#define OFF_XF     116391936u
#define OFF_H1     142344192u     /* fp32 h1 (25.95 MB) */
/* total 168,296,448 B */

// async global->LDS, 16B per lane; LDS dest = wave-uniform base + lane*16
__device__ __forceinline__ void gl2lds(const hb* g, hb* l) {
    __builtin_amdgcn_global_load_lds((const __attribute__((address_space(1))) unsigned int*)g,
                                     (__attribute__((address_space(3))) unsigned int*)l, 16, 0, 0);
}

// ---------------- small utility kernels ----------------

__global__ void cvt_bf16_kernel(const float* __restrict__ in, hb* __restrict__ out, int n) {
    int t = blockIdx.x * 256 + threadIdx.x;
    if (t < n) out[t] = __float2bfloat16(in[t]);
}

__global__ void patchify_kernel(const float* __restrict__ img, hb* __restrict__ Xp) {
    int t = blockIdx.x * 256 + threadIdx.x;
    if (t >= PROWS * 768) return;
    int r = t / 768, j = t % 768;
    int b = r / 196, p = r % 196;
    int ph = p / 14, pw = p % 14;
    int p1 = j / 48, jr = j % 48;
    int p2 = jr / 3, c = jr % 3;
    float v = img[(((size_t)b * 3 + c) * 224 + ph * 16 + p1) * 224 + pw * 16 + p2];
    Xp[t] = __float2bfloat16(v);
}

__global__ void cls_init_kernel(const float* __restrict__ cls, const float* __restrict__ pos,
                                float* __restrict__ xf, hb* __restrict__ xb) {
    int t = blockIdx.x * 256 + threadIdx.x;   // 64*512
    int b = t >> 9, c = t & 511;
    float v = cls[c] + pos[c];
    size_t off = ((size_t)b * N_TOK) * N_DIM + c;
    xf[off] = v;
    xb[off] = __float2bfloat16(v);
}

__global__ void zero_pads_kernel(float* __restrict__ xf, hb* __restrict__ xb, hb* __restrict__ ctx) {
    int t = blockIdx.x * 256 + threadIdx.x;   // 64*512 pad elements
    size_t off = (size_t)ROWS * N_DIM + t;
    xf[off] = 0.f;
    xb[off] = __float2bfloat16(0.f);
    ctx[off] = __float2bfloat16(0.f);
}

__global__ void extract_cls_kernel(const float* __restrict__ xf, float* __restrict__ out) {
    int t = blockIdx.x * 256 + threadIdx.x;   // 64*512
    int b = t >> 9, c = t & 511;
    out[t] = xf[((size_t)b * N_TOK) * N_DIM + c];
}

// ---------------- LayerNorm (fp32 in -> fp32 + bf16 out), 1 wave per row ----------------

__global__ void __launch_bounds__(256) ln_kernel(const float* __restrict__ in,
                                                 const float* __restrict__ w, const float* __restrict__ b,
                                                 float* __restrict__ outf, hb* __restrict__ outb, int rows) {
    int row = blockIdx.x * 4 + (threadIdx.x >> 6);
    int lane = threadIdx.x & 63;
    if (row >= rows) return;
    const float* p = in + (size_t)row * N_DIM;
    float4 v0 = *(const float4*)(p + lane * 8);
    float4 v1 = *(const float4*)(p + lane * 8 + 4);
    float xs[8] = {v0.x, v0.y, v0.z, v0.w, v1.x, v1.y, v1.z, v1.w};
    float s = 0.f, q = 0.f;
#pragma unroll
    for (int j = 0; j < 8; ++j) { s += xs[j]; q += xs[j] * xs[j]; }
#pragma unroll
    for (int o = 32; o > 0; o >>= 1) { s += __shfl_xor(s, o); q += __shfl_xor(q, o); }
    float mean = s * (1.f / 512.f);
    float var = q * (1.f / 512.f) - mean * mean;
    float r = rsqrtf(var + 1e-5f);
    float4 w0 = *(const float4*)(w + lane * 8);
    float4 w1 = *(const float4*)(w + lane * 8 + 4);
    float4 b0 = *(const float4*)(b + lane * 8);
    float4 b1 = *(const float4*)(b + lane * 8 + 4);
    float ws8[8] = {w0.x, w0.y, w0.z, w0.w, w1.x, w1.y, w1.z, w1.w};
    float bs8[8] = {b0.x, b0.y, b0.z, b0.w, b1.x, b1.y, b1.z, b1.w};
    float of[8] __attribute__((aligned(16)));
    hb tb[8] __attribute__((aligned(16)));
#pragma unroll
    for (int j = 0; j < 8; ++j) {
        float y = (xs[j] - mean) * r * ws8[j] + bs8[j];
        of[j] = y;
        tb[j] = __float2bfloat16(y);
    }
    *(float4*)(outf + (size_t)row * N_DIM + lane * 8)     = *(const float4*)&of[0];
    *(float4*)(outf + (size_t)row * N_DIM + lane * 8 + 4) = *(const float4*)&of[4];
    *(float4*)(outb + (size_t)row * N_DIM + lane * 8)     = *(const float4*)&tb[0];
}

// ---------------- GEMM: C[M,N] = A[M,K] @ B[N,K]^T + bias ----------------
// K-loop: global_load_lds width=16 staging, BK=32, XOR chunk swizzle.
// LDS tile row r holds its 4 16B-chunks permuted: chunk c at position c ^ ((r>>1)&3).
// Staging realizes this by permuting which global chunk each lane fetches
// (DMA dest is fixed lane*16). Fragment reads add one XOR and hit 32 banks
// 2-way max (free) instead of 8-way-on-2-banks.
// MODE 0: out_bf = acc + bias                      (qkv)
// MODE 1: out_bf = gelu_tanh(acc + bias)           (fc1)
// MODE 2: out_f32 = acc + bias + res_f32           (out_proj, fc2)
// MODE 3: patch embed: row remap + pos_emb, writes both f32 and bf16

template <int MODE>
__global__ void __launch_bounds__(256) gemm_bt(const hb* __restrict__ A, const hb* __restrict__ B,
                                               const float* __restrict__ bias, int K, int N,
                                               hb* __restrict__ outb, float* __restrict__ outf,
                                               const float* __restrict__ res, const float* __restrict__ pos) {
    __shared__ hb Sm[8192];          // As[128][32] | Bs[128][32]; reused as C-bounce in epilogue
    hb* As = Sm;
    hb* Bs = Sm + 4096;
    const int tid = threadIdx.x;
    const int lane = tid & 63, wid = tid >> 6;
    const int wr = wid >> 1, wc = wid & 1;
    const int quad = lane >> 4, r16 = lane & 15;
    const int m0 = blockIdx.y * 128, n0 = blockIdx.x * 128;

    // staging: wave w stages rows [32w,32w+32); one gl2lds = 16 rows (64 lanes x 16B).
    // lane l -> row +(l>>2), fetches global chunk (l&3) ^ ((l>>3)&3)  [swizzle]
    const int r0 = lane >> 2;
    const int c0 = (lane & 3) ^ ((lane >> 3) & 3);
    const hb* ga0 = A + (size_t)(m0 + wid * 32 + r0) * K + c0 * 8;
    const hb* ga1 = ga0 + (size_t)16 * K;
    const hb* gb0 = B + (size_t)(n0 + wid * 32 + r0) * K + c0 * 8;
    const hb* gb1 = gb0 + (size_t)16 * K;
    hb* la0 = As + (wid * 32) * 32;       // wave-uniform LDS bases
    hb* la1 = la0 + 16 * 32;
    hb* lb0 = Bs + (wid * 32) * 32;
    hb* lb1 = lb0 + 16 * 32;

    // fragment read positions: logical chunk quad at position quad ^ ((r16>>1)&3)
    const int sw = (r16 >> 1) & 3;
    const int pa = (quad ^ sw) * 8;

    f32x4 acc[4][4] = {};

    for (int k0 = 0; k0 < K; k0 += 32) {
        gl2lds(ga0, la0);
        gl2lds(ga1, la1);
        gl2lds(gb0, lb0);
        gl2lds(gb1, lb1);
        ga0 += 32; ga1 += 32; gb0 += 32; gb1 += 32;
        __syncthreads();
        bf16x8 af[4], bfr[4];
#pragma unroll
        for (int t = 0; t < 4; ++t) {
            af[t]  = *(const bf16x8*)&As[(wr * 64 + t * 16 + r16) * 32 + pa];
            bfr[t] = *(const bf16x8*)&Bs[(wc * 64 + t * 16 + r16) * 32 + pa];
        }
#pragma unroll
        for (int mi = 0; mi < 4; ++mi)
#pragma unroll
            for (int nj = 0; nj < 4; ++nj)
                acc[mi][nj] = __builtin_amdgcn_mfma_f32_16x16x32_bf16(af[mi], bfr[nj], acc[mi][nj], 0, 0, 0);
        __syncthreads();
    }

    if constexpr (MODE == 0 || MODE == 1) {
        // coalesced epilogue: per-wave 64x32 LDS bounce (wave-private, in-order LDS)
        hb* Cb = Sm + wid * 2048;
#pragma unroll
        for (int p = 0; p < 2; ++p) {
#pragma unroll
            for (int nj2 = 0; nj2 < 2; ++nj2) {
                int nj = p * 2 + nj2;
                float bv = bias[n0 + wc * 64 + nj * 16 + r16];
#pragma unroll
                for (int mi = 0; mi < 4; ++mi)
#pragma unroll
                    for (int e = 0; e < 4; ++e) {
                        float v = acc[mi][nj][e] + bv;
                        if constexpr (MODE == 1) {
                            // tanh-form GELU (max dev vs erf ~3e-4)
                            float y = 0.79788456f * (v + 0.044715f * v * v * v);
                            float t = 1.f - 2.f / (__expf(2.f * y) + 1.f);
                            v = 0.5f * v * (1.f + t);
                        }
                        Cb[(mi * 16 + quad * 4 + e) * 32 + nj2 * 16 + r16] = __float2bfloat16(v);
                    }
            }
#pragma unroll
            for (int it = 0; it < 4; ++it) {
                int idx = it * 64 + lane;
                int row = idx >> 2, ch = idx & 3;
                bf16x8 val = *(const bf16x8*)&Cb[row * 32 + ch * 8];
                *(bf16x8*)(outb + (size_t)(m0 + wr * 64 + row) * N + n0 + wc * 64 + p * 32 + ch * 8) = val;
            }
        }
    } else if constexpr (MODE == 2) {
#pragma unroll
        for (int nj = 0; nj < 4; ++nj) {
            int col = n0 + wc * 64 + nj * 16 + r16;
            float bv = bias[col];
#pragma unroll
            for (int mi = 0; mi < 4; ++mi)
#pragma unroll
                for (int e = 0; e < 4; ++e) {
                    int row = m0 + wr * 64 + mi * 16 + quad * 4 + e;
                    outf[(size_t)row * N + col] = acc[mi][nj][e] + bv + res[(size_t)row * N + col];
                }
        }
    } else {  // MODE 3: patch embed
#pragma unroll
        for (int nj = 0; nj < 4; ++nj) {
            int col = n0 + wc * 64 + nj * 16 + r16;
            float bv = bias[col];
#pragma unroll
            for (int mi = 0; mi < 4; ++mi)
#pragma unroll
                for (int e = 0; e < 4; ++e) {
                    int row = m0 + wr * 64 + mi * 16 + quad * 4 + e;
                    float v = acc[mi][nj][e] + bv;
                    int pidx = row % 196;
                    int row2 = row + row / 196 + 1;
                    v += pos[(size_t)(pidx + 1) * N_DIM + col];
                    outf[(size_t)row2 * N_DIM + col] = v;
                    outb[(size_t)row2 * N_DIM + col] = __float2bfloat16(v);
                }
        }
    }
}

// ---------------- MFMA flash attention: one block per (b, h) ----------------
// qkv row: [q(512)|k(512)|v(512)], head h at cols h*64..h*64+63.
// K and V both staged row-major [m][d] from qkv; PV B-fragment gathered from
// Vs via 8 x ds_read_u16 (2B stride across 16 lanes -> 2-way bank, free).

__global__ void __launch_bounds__(256, 2) attn_kernel(const hb* __restrict__ qkv,
                                                      hb* __restrict__ ctx) {
    __shared__ hb Ks[224 * 64];      // K [key][d]   28,672 B
    __shared__ hb Vs[224 * 64];      // V [key][d]   28,672 B
    __shared__ hb Pb[4][16 * 40];    // per-wave P bounce
    const int bh = blockIdx.x;
    const int b = bh >> 3, h = bh & 7;
    const int tid = threadIdx.x, lane = tid & 63, wid = tid >> 6;
    const int quad = lane >> 4, r16 = lane & 15;
    const hb* base = qkv + (size_t)(b * N_TOK) * 1536 + h * 64;

#pragma unroll
    for (int i = 0; i < 7; ++i) {
        int idx = tid + i * 256;               // 1792 16B chunks
        int m = idx >> 3, c = idx & 7;
        bf16x8 kv = {}, vv = {};
        if (m < 197) {
            kv = *(const bf16x8*)(base + (size_t)m * 1536 + 512 + c * 8);
            vv = *(const bf16x8*)(base + (size_t)m * 1536 + 1024 + c * 8);
        }
        *(bf16x8*)&Ks[m * 64 + c * 8] = kv;
        *(bf16x8*)&Vs[m * 64 + c * 8] = vv;
    }

    // Q fragments: 64 query rows per wave
    bf16x8 af[4][2];
#pragma unroll
    for (int mi = 0; mi < 4; ++mi) {
        int q = wid * 64 + mi * 16 + r16;
#pragma unroll
        for (int kc = 0; kc < 2; ++kc)
            af[mi][kc] = *(const bf16x8*)(base + (size_t)q * 1536 + kc * 32 + quad * 8);
    }

    f32x4 o[4][4] = {};
    float mst[4][4], lp[4][4];
#pragma unroll
    for (int mi = 0; mi < 4; ++mi)
#pragma unroll
        for (int e = 0; e < 4; ++e) { mst[mi][e] = -3.0e38f; lp[mi][e] = 0.f; }

    __syncthreads();

    const __bf16* VsB = (const __bf16*)Vs;
    for (int kt = 0; kt < 7; ++kt) {
        bf16x8 bk[2][2], bv[4];
#pragma unroll
        for (int nj = 0; nj < 2; ++nj)
#pragma unroll
            for (int kc = 0; kc < 2; ++kc)
                bk[nj][kc] = *(const bf16x8*)&Ks[(kt * 32 + nj * 16 + r16) * 64 + kc * 32 + quad * 8];
        // PV B-frag: B[k=m][n=d], lane holds d=jd*16+r16, k=kt*32+quad*8+j
#pragma unroll
        for (int jd = 0; jd < 4; ++jd) {
            bf16x8 t;
#pragma unroll
            for (int j = 0; j < 8; ++j)
                t[j] = VsB[(kt * 32 + quad * 8 + j) * 64 + jd * 16 + r16];
            bv[jd] = t;
        }

        const bool v0 = (kt * 32 + r16) < N_TOK;
        const bool v1 = (kt * 32 + 16 + r16) < N_TOK;

#pragma unroll
        for (int mi = 0; mi < 4; ++mi) {
            f32x4 z = {};
            f32x4 s0v = __builtin_amdgcn_mfma_f32_16x16x32_bf16(af[mi][0], bk[0][0], z, 0, 0, 0);
            s0v = __builtin_amdgcn_mfma_f32_16x16x32_bf16(af[mi][1], bk[0][1], s0v, 0, 0, 0);
            f32x4 s1v = __builtin_amdgcn_mfma_f32_16x16x32_bf16(af[mi][0], bk[1][0], z, 0, 0, 0);
            s1v = __builtin_amdgcn_mfma_f32_16x16x32_bf16(af[mi][1], bk[1][1], s1v, 0, 0, 0);

            float al[4];
#pragma unroll
            for (int e = 0; e < 4; ++e) {
                float s0 = v0 ? s0v[e] * 0.125f : -1e30f;
                float s1 = v1 ? s1v[e] * 0.125f : -1e30f;
                float mx = fmaxf(s0, s1);
#pragma unroll
                for (int off = 1; off < 16; off <<= 1) mx = fmaxf(mx, __shfl_xor(mx, off));
                float mnew = fmaxf(mst[mi][e], mx);
                float alpha = __expf(mst[mi][e] - mnew);
                mst[mi][e] = mnew;
                float p0 = __expf(s0 - mnew);
                float p1 = __expf(s1 - mnew);
                lp[mi][e] = lp[mi][e] * alpha + p0 + p1;
                al[e] = alpha;
                int prow = (quad * 4 + e) * 40;
                Pb[wid][prow + r16]      = __float2bfloat16(p0);
                Pb[wid][prow + 16 + r16] = __float2bfloat16(p1);
            }
#pragma unroll
            for (int jd = 0; jd < 4; ++jd)
#pragma unroll
                for (int e = 0; e < 4; ++e) o[mi][jd][e] *= al[e];
            bf16x8 ap = *(const bf16x8*)&Pb[wid][r16 * 40 + quad * 8];
#pragma unroll
            for (int jd = 0; jd < 4; ++jd)
                o[mi][jd] = __builtin_amdgcn_mfma_f32_16x16x32_bf16(ap, bv[jd], o[mi][jd], 0, 0, 0);
        }
    }

#pragma unroll
    for (int mi = 0; mi < 4; ++mi) {
        float rl[4];
#pragma unroll
        for (int e = 0; e < 4; ++e) {
            float l = lp[mi][e];
#pragma unroll
            for (int off = 1; off < 16; off <<= 1) l += __shfl_xor(l, off);
            rl[e] = 1.f / l;
        }
        int qrow = wid * 64 + mi * 16 + quad * 4;
#pragma unroll
        for (int e = 0; e < 4; ++e) {
            int q = qrow + e;
            if (q < N_TOK) {
                hb* dst = ctx + ((size_t)(b * N_TOK + q)) * N_DIM + h * 64;
#pragma unroll
                for (int jd = 0; jd < 4; ++jd)
                    dst[jd * 16 + r16] = __float2bfloat16(o[mi][jd][e] * rl[e]);
            }
        }
    }
}

// ---------------- launch ----------------

extern "C" void kernel_launch(void* const* d_in, const int* in_sizes, int n_in,
                              void* d_out, int out_size, void* d_ws, size_t ws_size,
                              hipStream_t stream) {
    (void)in_sizes; (void)n_in; (void)out_size; (void)ws_size;
    const float* img     = (const float*)d_in[0];
    const float* patch_w = (const float*)d_in[1];
    const float* patch_b = (const float*)d_in[2];
    const float* cls_t   = (const float*)d_in[3];
    const float* pos     = (const float*)d_in[4];
    const float* w_qkv   = (const float*)d_in[5];
    const float* b_qkv   = (const float*)d_in[6];
    const float* w_out   = (const float*)d_in[7];
    const float* b_out   = (const float*)d_in[8];
    const float* ln1w    = (const float*)d_in[9];
    const float* ln1b    = (const float*)d_in[10];
    const float* w_fc1   = (const float*)d_in[11];
    const float* b_fc1   = (const float*)d_in[12];
    const float* w_fc2   = (const float*)d_in[13];
    const float* b_fc2   = (const float*)d_in[14];
    const float* ln2w    = (const float*)d_in[15];
    const float* ln2b    = (const float*)d_in[16];

    char* ws = (char*)d_ws;
    hb* wPatch = (hb*)(ws + OFF_WPATCH);
    hb* wQKV   = (hb*)(ws + OFF_WQKV);
    hb* wOut   = (hb*)(ws + OFF_WOUT);
    hb* wFc1   = (hb*)(ws + OFF_WFC1);
    hb* wFc2   = (hb*)(ws + OFF_WFC2);
    hb* x_bf   = (hb*)(ws + OFF_XBF);
    hb* ctx    = (hb*)(ws + OFF_CTX);
    hb* Xp     = (hb*)(ws + OFF_BIG);
    hb* qkv    = (hb*)(ws + OFF_BIG);
    hb* hmid   = (hb*)(ws + OFF_BIG);
    float* x_f = (float*)(ws + OFF_XF);
    float* h1  = (float*)(ws + OFF_H1);

    auto cvt = [&](const float* src, hb* dst, int n) {
        cvt_bf16_kernel<<<dim3((n + 255) / 256), dim3(256), 0, stream>>>(src, dst, n);
    };
    cvt(patch_w, wPatch, 512 * 768);
    cvt(w_qkv, wQKV, N_DEPTH * 1536 * 512);
    cvt(w_out, wOut, N_DEPTH * 512 * 512);
    cvt(w_fc1, wFc1, N_DEPTH * 2048 * 512);
    cvt(w_fc2, wFc2, N_DEPTH * 512 * 2048);

    patchify_kernel<<<dim3((PROWS * 768 + 255) / 256), dim3(256), 0, stream>>>(img, Xp);
    gemm_bt<3><<<dim3(4, 98), dim3(256), 0, stream>>>(Xp, wPatch, patch_b, 768, 512,
                                                      x_bf, x_f, nullptr, pos);
    cls_init_kernel<<<dim3(128), dim3(256), 0, stream>>>(cls_t, pos, x_f, x_bf);
    zero_pads_kernel<<<dim3(128), dim3(256), 0, stream>>>(x_f, x_bf, ctx);

    for (int i = 0; i < N_DEPTH; ++i) {
        gemm_bt<0><<<dim3(12, 99), dim3(256), 0, stream>>>(x_bf, wQKV + (size_t)i * 1536 * 512,
                                                           b_qkv + i * 1536, 512, 1536,
                                                           qkv, nullptr, nullptr, nullptr);
        attn_kernel<<<dim3(512), dim3(256), 0, stream>>>(qkv, ctx);
        gemm_bt<2><<<dim3(4, 99), dim3(256), 0, stream>>>(ctx, wOut + (size_t)i * 512 * 512,
                                                          b_out + i * 512, 512, 512,
                                                          nullptr, h1, x_f, nullptr);
        ln_kernel<<<dim3(3152), dim3(256), 0, stream>>>(h1, ln1w + i * 512, ln1b + i * 512, x_f, x_bf, ROWS);
        gemm_bt<1><<<dim3(16, 99), dim3(256), 0, stream>>>(x_bf, wFc1 + (size_t)i * 2048 * 512,
                                                           b_fc1 + i * 2048, 512, 2048,
                                                           hmid, nullptr, nullptr, nullptr);
        gemm_bt<2><<<dim3(4, 99), dim3(256), 0, stream>>>(hmid, wFc2 + (size_t)i * 512 * 2048,
                                                          b_fc2 + i * 512, 2048, 512,
                                                          nullptr, h1, x_f, nullptr);
        ln_kernel<<<dim3(3152), dim3(256), 0, stream>>>(h1, ln2w + i * 512, ln2b + i * 512, x_f, x_bf, ROWS);
    }

    extract_cls_kernel<<<dim3(128), dim3(256), 0, stream>>>(x_f, (float*)d_out);
}

// Round 7
// 1489.137 us; speedup vs baseline: 1.2300x; 1.0531x over previous
//
#include <hip/hip_runtime.h>
#include <hip/hip_bf16.h>

typedef __hip_bfloat16 hb;
typedef __bf16 bf16x8 __attribute__((ext_vector_type(8)));
typedef float f32x4 __attribute__((ext_vector_type(4)));

#define N_DEPTH 6
#define N_DIM   512
#define N_HEADS 8
#define N_MLP   2048
#define N_TOK   197
#define N_PATCH 196
#define N_BATCH 64
#define ROWS    (N_BATCH * N_TOK)     /* 12608 */
#define ROWS_PAD 12672                /* 99 * 128 */
#define PROWS   (N_BATCH * N_PATCH)   /* 12544 = 98 * 128 */

// ---------------- workspace layout (bytes) ----------------
#define OFF_WPATCH 0u
#define OFF_WQKV   786432u
#define OFF_WOUT   10223616u
#define OFF_WFC1   13369344u
#define OFF_WFC2   25952256u
#define OFF_XBF    38535168u          /* x_bf swizzled A-layout (K=512) */
#define OFF_CTX    51511296u          /* ctx  swizzled A-layout (K=512) */
#define OFF_BIG    64487424u          /* Xp / qkv(row-major) / hmid swizzled (51.9 MB) */
#define OFF_XF     116391936u
#define OFF_H1     142344192u
/* total 168,296,448 B */

// Swizzled A/B fragment layout for 16x16x32 MFMA (KB = K/32):
// elem(row r, col k) -> (((mb*KB + kb)*2 + wr)*4 + t)*512 + quad*128 + r16*8 + e
//   mb=r>>7, wr=(r>>6)&1, t=(r>>4)&3, r16=r&15, kb=k>>5, quad=(k>>3)&3, e=k&7
// A wave fragment read = contiguous 1 KB (lane*16B).
__device__ __forceinline__ size_t swoff(int row, int k, int KB) {
    return (size_t)((((row >> 7) * KB + (k >> 5)) * 2 + ((row >> 6) & 1)) * 4 + ((row >> 4) & 3)) * 512
           + ((k >> 3) & 3) * 128 + (row & 15) * 8 + (k & 7);
}

// async global->LDS, 16B per lane (patch-embed GEMM only)
__device__ __forceinline__ void gl2lds(const hb* g, hb* l) {
    __builtin_amdgcn_global_load_lds((const __attribute__((address_space(1))) unsigned int*)g,
                                     (__attribute__((address_space(3))) unsigned int*)l, 16, 0, 0);
}

// ---------------- weight swizzle (fp32 row-major -> bf16 fragment order) ----------------

__global__ void wsw_kernel(const float* __restrict__ W, hb* __restrict__ out, int K, int N) {
    const int layer = blockIdx.y;
    const float* Wl = W + (size_t)layer * N * K;
    hb* ol = out + (size_t)layer * N * K;
    int idx = blockIdx.x * 256 + threadIdx.x;
    if (idx >= N * (K >> 3)) return;
    int n = idx / (K >> 3), kc = idx % (K >> 3);
    int k = kc * 8;
    hb tmp[8] __attribute__((aligned(16)));
#pragma unroll
    for (int j = 0; j < 8; ++j) tmp[j] = __float2bfloat16(Wl[(size_t)n * K + k + j]);
    *(float4*)(ol + swoff(n, k, K >> 5)) = *(const float4*)tmp;
}

__global__ void cvt_bf16_kernel(const float* __restrict__ in, hb* __restrict__ out, int n) {
    int t = blockIdx.x * 256 + threadIdx.x;
    if (t < n) out[t] = __float2bfloat16(in[t]);
}

// ---------------- small utility kernels ----------------

__global__ void patchify_kernel(const float* __restrict__ img, hb* __restrict__ Xp) {
    int t = blockIdx.x * 256 + threadIdx.x;
    if (t >= PROWS * 768) return;
    int r = t / 768, j = t % 768;
    int b = r / 196, p = r % 196;
    int ph = p / 14, pw = p % 14;
    int p1 = j / 48, jr = j % 48;
    int p2 = jr / 3, c = jr % 3;
    float v = img[(((size_t)b * 3 + c) * 224 + ph * 16 + p1) * 224 + pw * 16 + p2];
    Xp[t] = __float2bfloat16(v);
}

__global__ void cls_init_kernel(const float* __restrict__ cls, const float* __restrict__ pos,
                                float* __restrict__ xf, hb* __restrict__ xb) {
    int t = blockIdx.x * 256 + threadIdx.x;   // 64*512
    int b = t >> 9, c = t & 511;
    float v = cls[c] + pos[c];
    int row = b * N_TOK;
    xf[(size_t)row * N_DIM + c] = v;
    xb[swoff(row, c, 16)] = __float2bfloat16(v);
}

__global__ void zero_pads_kernel(float* __restrict__ xf, hb* __restrict__ xb, hb* __restrict__ ctx) {
    int t = blockIdx.x * 256 + threadIdx.x;   // 64*512 elements
    // fp32 pads row-major
    xf[(size_t)ROWS * N_DIM + t] = 0.f;
    // swizzled pads: rows 12608..12671 = mb 98, wr 1: contiguous per (kb)
    int kb = t >> 11, r2 = t & 2047;
    size_t off = (size_t)((98 * 16 + kb) * 2 + 1) * 2048 + r2;
    hb z = __float2bfloat16(0.f);
    xb[off] = z;
    ctx[off] = z;
}

__global__ void extract_cls_kernel(const float* __restrict__ xf, float* __restrict__ out) {
    int t = blockIdx.x * 256 + threadIdx.x;   // 64*512
    int b = t >> 9, c = t & 511;
    out[t] = xf[((size_t)b * N_TOK) * N_DIM + c];
}

// ---------------- LayerNorm (fp32 in -> fp32 row + bf16 swizzled), 1 wave per row ----------------

__global__ void __launch_bounds__(256) ln_kernel(const float* __restrict__ in,
                                                 const float* __restrict__ w, const float* __restrict__ b,
                                                 float* __restrict__ outf, hb* __restrict__ outb, int rows) {
    int row = blockIdx.x * 4 + (threadIdx.x >> 6);
    int lane = threadIdx.x & 63;
    if (row >= rows) return;
    const float* p = in + (size_t)row * N_DIM;
    float4 v0 = *(const float4*)(p + lane * 8);
    float4 v1 = *(const float4*)(p + lane * 8 + 4);
    float xs[8] = {v0.x, v0.y, v0.z, v0.w, v1.x, v1.y, v1.z, v1.w};
    float s = 0.f, q = 0.f;
#pragma unroll
    for (int j = 0; j < 8; ++j) { s += xs[j]; q += xs[j] * xs[j]; }
#pragma unroll
    for (int o = 32; o > 0; o >>= 1) { s += __shfl_xor(s, o); q += __shfl_xor(q, o); }
    float mean = s * (1.f / 512.f);
    float var = q * (1.f / 512.f) - mean * mean;
    float r = rsqrtf(var + 1e-5f);
    float4 w0 = *(const float4*)(w + lane * 8);
    float4 w1 = *(const float4*)(w + lane * 8 + 4);
    float4 b0 = *(const float4*)(b + lane * 8);
    float4 b1 = *(const float4*)(b + lane * 8 + 4);
    float ws8[8] = {w0.x, w0.y, w0.z, w0.w, w1.x, w1.y, w1.z, w1.w};
    float bs8[8] = {b0.x, b0.y, b0.z, b0.w, b1.x, b1.y, b1.z, b1.w};
    float of[8] __attribute__((aligned(16)));
    hb tb[8] __attribute__((aligned(16)));
#pragma unroll
    for (int j = 0; j < 8; ++j) {
        float y = (xs[j] - mean) * r * ws8[j] + bs8[j];
        of[j] = y;
        tb[j] = __float2bfloat16(y);
    }
    *(float4*)(outf + (size_t)row * N_DIM + lane * 8)     = *(const float4*)&of[0];
    *(float4*)(outf + (size_t)row * N_DIM + lane * 8 + 4) = *(const float4*)&of[4];
    // swizzled bf16 store: lane holds cols lane*8..+7 -> kb=lane>>2, quad=lane&3
    *(float4*)(outb + swoff(row, lane * 8, 16)) = *(const float4*)tb;
}

// ---------------- barrier-free swizzled GEMM ----------------
// A, B both in fragment-swizzled layout. K-loop: 8 coalesced dwordx4 loads +
// 16 MFMA, manual next-iter prefetch, NO LDS, NO barriers.
// MODE 0: out_bf row-major = acc + bias            (qkv)
// MODE 1: out_bf SWIZZLED = gelu_tanh(acc + bias)  (fc1 -> hmid, consumer K=N)
// MODE 2: out_f32 row-major = acc + bias + res     (out_proj, fc2)

template <int K, int MODE>
__global__ void __launch_bounds__(256) gemm_sw(const hb* __restrict__ A, const hb* __restrict__ B,
                                               const float* __restrict__ bias, int N,
                                               hb* __restrict__ outb, float* __restrict__ outf,
                                               const float* __restrict__ res) {
    constexpr int KB = K / 32;
    __shared__ hb Sm[4][2560];       // per-wave epilogue bounce, stride 40 (MODE 0/1)
    const int tid = threadIdx.x;
    const int lane = tid & 63, wid = tid >> 6;
    const int wr = wid >> 1, wc = wid & 1;
    const int quad = lane >> 4, r16 = lane & 15;
    const int mb = blockIdx.y, nb = blockIdx.x;
    const int m0 = mb * 128, n0 = nb * 128;

    const hb* pa = A + (size_t)mb * KB * 4096 + wr * 2048 + lane * 8;
    const hb* pb = B + (size_t)nb * KB * 4096 + wc * 2048 + lane * 8;

    f32x4 acc[4][4] = {};
    bf16x8 af[4], bfr[4];
#pragma unroll
    for (int t = 0; t < 4; ++t) {
        af[t]  = *(const bf16x8*)(pa + t * 512);
        bfr[t] = *(const bf16x8*)(pb + t * 512);
    }
#pragma unroll 2
    for (int kb = 0; kb < KB; ++kb) {
        bf16x8 an[4], bn[4];
        if (kb + 1 < KB) {
            size_t o = (size_t)(kb + 1) * 4096;
#pragma unroll
            for (int t = 0; t < 4; ++t) {
                an[t] = *(const bf16x8*)(pa + o + t * 512);
                bn[t] = *(const bf16x8*)(pb + o + t * 512);
            }
        }
#pragma unroll
        for (int mi = 0; mi < 4; ++mi)
#pragma unroll
            for (int nj = 0; nj < 4; ++nj)
                acc[mi][nj] = __builtin_amdgcn_mfma_f32_16x16x32_bf16(af[mi], bfr[nj], acc[mi][nj], 0, 0, 0);
        if (kb + 1 < KB) {
#pragma unroll
            for (int t = 0; t < 4; ++t) { af[t] = an[t]; bfr[t] = bn[t]; }
        }
    }

    if constexpr (MODE == 0 || MODE == 1) {
        hb* Cb = &Sm[wid][0];
#pragma unroll
        for (int p = 0; p < 2; ++p) {
#pragma unroll
            for (int nj2 = 0; nj2 < 2; ++nj2) {
                int nj = p * 2 + nj2;
                float bv = bias[n0 + wc * 64 + nj * 16 + r16];
#pragma unroll
                for (int mi = 0; mi < 4; ++mi)
#pragma unroll
                    for (int e = 0; e < 4; ++e) {
                        float v = acc[mi][nj][e] + bv;
                        if constexpr (MODE == 1) {
                            float y = 0.79788456f * (v + 0.044715f * v * v * v);
                            float t = 1.f - 2.f / (__expf(2.f * y) + 1.f);
                            v = 0.5f * v * (1.f + t);
                        }
                        Cb[(mi * 16 + quad * 4 + e) * 40 + nj2 * 16 + r16] = __float2bfloat16(v);
                    }
            }
            if constexpr (MODE == 0) {
#pragma unroll
                for (int it = 0; it < 4; ++it) {
                    int idx = it * 64 + lane;
                    int row = idx >> 2, ch = idx & 3;
                    bf16x8 val = *(const bf16x8*)&Cb[row * 40 + ch * 8];
                    *(bf16x8*)(outb + (size_t)(m0 + wr * 64 + row) * N + n0 + wc * 64 + p * 32 + ch * 8) = val;
                }
            } else {
                // swizzled coalesced store: this 64x32 strip == frag group
                // (mb, kb=(n0+wc*64+p*32)/32, wr, t=it); 1 KB contiguous per wave
                size_t base = ((((size_t)mb * (N >> 5) + ((n0 + wc * 64 + p * 32) >> 5)) * 2 + wr) * 4) * 512;
#pragma unroll
                for (int it = 0; it < 4; ++it) {
                    bf16x8 val = *(const bf16x8*)&Cb[(it * 16 + r16) * 40 + quad * 8];
                    *(bf16x8*)(outb + base + it * 512 + lane * 8) = val;
                }
            }
        }
    } else {  // MODE 2
#pragma unroll
        for (int nj = 0; nj < 4; ++nj) {
            int col = n0 + wc * 64 + nj * 16 + r16;
            float bv = bias[col];
#pragma unroll
            for (int mi = 0; mi < 4; ++mi)
#pragma unroll
                for (int e = 0; e < 4; ++e) {
                    int row = m0 + wr * 64 + mi * 16 + quad * 4 + e;
                    outf[(size_t)row * N + col] = acc[mi][nj][e] + bv + res[(size_t)row * N + col];
                }
        }
    }
}

// ---------------- patch-embed GEMM (LDS-staged, XOR swizzle; runs once) ----------------
// C = Xp @ patch_w^T + bias + pos, row-remapped; writes x_f rows + x_bf swizzled.

__global__ void __launch_bounds__(256) gemm_pe(const hb* __restrict__ A, const hb* __restrict__ B,
                                               const float* __restrict__ bias, int K, int N,
                                               hb* __restrict__ outb, float* __restrict__ outf,
                                               const float* __restrict__ pos) {
    __shared__ hb Sm[8192];
    hb* As = Sm;
    hb* Bs = Sm + 4096;
    const int tid = threadIdx.x;
    const int lane = tid & 63, wid = tid >> 6;
    const int wr = wid >> 1, wc = wid & 1;
    const int quad = lane >> 4, r16 = lane & 15;
    const int m0 = blockIdx.y * 128, n0 = blockIdx.x * 128;

    const int r0 = lane >> 2;
    const int c0 = (lane & 3) ^ ((lane >> 3) & 3);
    const hb* ga0 = A + (size_t)(m0 + wid * 32 + r0) * K + c0 * 8;
    const hb* ga1 = ga0 + (size_t)16 * K;
    const hb* gb0 = B + (size_t)(n0 + wid * 32 + r0) * K + c0 * 8;
    const hb* gb1 = gb0 + (size_t)16 * K;
    hb* la0 = As + (wid * 32) * 32;
    hb* la1 = la0 + 16 * 32;
    hb* lb0 = Bs + (wid * 32) * 32;
    hb* lb1 = lb0 + 16 * 32;
    const int sw = (r16 >> 1) & 3;
    const int pa = (quad ^ sw) * 8;

    f32x4 acc[4][4] = {};
    for (int k0 = 0; k0 < K; k0 += 32) {
        gl2lds(ga0, la0);
        gl2lds(ga1, la1);
        gl2lds(gb0, lb0);
        gl2lds(gb1, lb1);
        ga0 += 32; ga1 += 32; gb0 += 32; gb1 += 32;
        __syncthreads();
        bf16x8 af[4], bfr[4];
#pragma unroll
        for (int t = 0; t < 4; ++t) {
            af[t]  = *(const bf16x8*)&As[(wr * 64 + t * 16 + r16) * 32 + pa];
            bfr[t] = *(const bf16x8*)&Bs[(wc * 64 + t * 16 + r16) * 32 + pa];
        }
#pragma unroll
        for (int mi = 0; mi < 4; ++mi)
#pragma unroll
            for (int nj = 0; nj < 4; ++nj)
                acc[mi][nj] = __builtin_amdgcn_mfma_f32_16x16x32_bf16(af[mi], bfr[nj], acc[mi][nj], 0, 0, 0);
        __syncthreads();
    }

#pragma unroll
    for (int nj = 0; nj < 4; ++nj) {
        int col = n0 + wc * 64 + nj * 16 + r16;
        float bv = bias[col];
#pragma unroll
        for (int mi = 0; mi < 4; ++mi)
#pragma unroll
            for (int e = 0; e < 4; ++e) {
                int row = m0 + wr * 64 + mi * 16 + quad * 4 + e;
                float v = acc[mi][nj][e] + bv;
                int pidx = row % 196;
                int row2 = row + row / 196 + 1;
                v += pos[(size_t)(pidx + 1) * N_DIM + col];
                outf[(size_t)row2 * N_DIM + col] = v;
                outb[swoff(row2, col, 16)] = __float2bfloat16(v);
            }
    }
}

// ---------------- MFMA flash attention: one block per (b, h) ----------------
// qkv row-major: [q(512)|k(512)|v(512)]; ctx written SWIZZLED (out_proj A input).

__global__ void __launch_bounds__(256, 2) attn_kernel(const hb* __restrict__ qkv,
                                                      hb* __restrict__ ctx) {
    __shared__ hb Ks[224 * 64];
    __shared__ hb Vs[224 * 64];
    __shared__ hb Pb[4][16 * 40];
    const int bh = blockIdx.x;
    const int b = bh >> 3, h = bh & 7;
    const int tid = threadIdx.x, lane = tid & 63, wid = tid >> 6;
    const int quad = lane >> 4, r16 = lane & 15;
    const hb* base = qkv + (size_t)(b * N_TOK) * 1536 + h * 64;

#pragma unroll
    for (int i = 0; i < 7; ++i) {
        int idx = tid + i * 256;
        int m = idx >> 3, c = idx & 7;
        bf16x8 kv = {}, vv = {};
        if (m < 197) {
            kv = *(const bf16x8*)(base + (size_t)m * 1536 + 512 + c * 8);
            vv = *(const bf16x8*)(base + (size_t)m * 1536 + 1024 + c * 8);
        }
        *(bf16x8*)&Ks[m * 64 + c * 8] = kv;
        *(bf16x8*)&Vs[m * 64 + c * 8] = vv;
    }

    bf16x8 af[4][2];
#pragma unroll
    for (int mi = 0; mi < 4; ++mi) {
        int q = wid * 64 + mi * 16 + r16;
#pragma unroll
        for (int kc = 0; kc < 2; ++kc)
            af[mi][kc] = *(const bf16x8*)(base + (size_t)q * 1536 + kc * 32 + quad * 8);
    }

    f32x4 o[4][4] = {};
    float mst[4][4], lp[4][4];
#pragma unroll
    for (int mi = 0; mi < 4; ++mi)
#pragma unroll
        for (int e = 0; e < 4; ++e) { mst[mi][e] = -3.0e38f; lp[mi][e] = 0.f; }

    __syncthreads();

    const __bf16* VsB = (const __bf16*)Vs;
    for (int kt = 0; kt < 7; ++kt) {
        bf16x8 bk[2][2], bv[4];
#pragma unroll
        for (int nj = 0; nj < 2; ++nj)
#pragma unroll
            for (int kc = 0; kc < 2; ++kc)
                bk[nj][kc] = *(const bf16x8*)&Ks[(kt * 32 + nj * 16 + r16) * 64 + kc * 32 + quad * 8];
#pragma unroll
        for (int jd = 0; jd < 4; ++jd) {
            bf16x8 t;
#pragma unroll
            for (int j = 0; j < 8; ++j)
                t[j] = VsB[(kt * 32 + quad * 8 + j) * 64 + jd * 16 + r16];
            bv[jd] = t;
        }

        const bool v0 = (kt * 32 + r16) < N_TOK;
        const bool v1 = (kt * 32 + 16 + r16) < N_TOK;

#pragma unroll
        for (int mi = 0; mi < 4; ++mi) {
            f32x4 z = {};
            f32x4 s0v = __builtin_amdgcn_mfma_f32_16x16x32_bf16(af[mi][0], bk[0][0], z, 0, 0, 0);
            s0v = __builtin_amdgcn_mfma_f32_16x16x32_bf16(af[mi][1], bk[0][1], s0v, 0, 0, 0);
            f32x4 s1v = __builtin_amdgcn_mfma_f32_16x16x32_bf16(af[mi][0], bk[1][0], z, 0, 0, 0);
            s1v = __builtin_amdgcn_mfma_f32_16x16x32_bf16(af[mi][1], bk[1][1], s1v, 0, 0, 0);

            float al[4];
#pragma unroll
            for (int e = 0; e < 4; ++e) {
                float s0 = v0 ? s0v[e] * 0.125f : -1e30f;
                float s1 = v1 ? s1v[e] * 0.125f : -1e30f;
                float mx = fmaxf(s0, s1);
#pragma unroll
                for (int off = 1; off < 16; off <<= 1) mx = fmaxf(mx, __shfl_xor(mx, off));
                float mnew = fmaxf(mst[mi][e], mx);
                float alpha = __expf(mst[mi][e] - mnew);
                mst[mi][e] = mnew;
                float p0 = __expf(s0 - mnew);
                float p1 = __expf(s1 - mnew);
                lp[mi][e] = lp[mi][e] * alpha + p0 + p1;
                al[e] = alpha;
                int prow = (quad * 4 + e) * 40;
                Pb[wid][prow + r16]      = __float2bfloat16(p0);
                Pb[wid][prow + 16 + r16] = __float2bfloat16(p1);
            }
#pragma unroll
            for (int jd = 0; jd < 4; ++jd)
#pragma unroll
                for (int e = 0; e < 4; ++e) o[mi][jd][e] *= al[e];
            bf16x8 ap = *(const bf16x8*)&Pb[wid][r16 * 40 + quad * 8];
#pragma unroll
            for (int jd = 0; jd < 4; ++jd)
                o[mi][jd] = __builtin_amdgcn_mfma_f32_16x16x32_bf16(ap, bv[jd], o[mi][jd], 0, 0, 0);
        }
    }

#pragma unroll
    for (int mi = 0; mi < 4; ++mi) {
        float rl[4];
#pragma unroll
        for (int e = 0; e < 4; ++e) {
            float l = lp[mi][e];
#pragma unroll
            for (int off = 1; off < 16; off <<= 1) l += __shfl_xor(l, off);
            rl[e] = 1.f / l;
        }
        int qrow = wid * 64 + mi * 16 + quad * 4;
#pragma unroll
        for (int e = 0; e < 4; ++e) {
            int q = qrow + e;
            if (q < N_TOK) {
                int row = b * N_TOK + q;
#pragma unroll
                for (int jd = 0; jd < 4; ++jd)
                    ctx[swoff(row, h * 64 + jd * 16 + r16, 16)] = __float2bfloat16(o[mi][jd][e] * rl[e]);
            }
        }
    }
}

// ---------------- launch ----------------

extern "C" void kernel_launch(void* const* d_in, const int* in_sizes, int n_in,
                              void* d_out, int out_size, void* d_ws, size_t ws_size,
                              hipStream_t stream) {
    (void)in_sizes; (void)n_in; (void)out_size; (void)ws_size;
    const float* img     = (const float*)d_in[0];
    const float* patch_w = (const float*)d_in[1];
    const float* patch_b = (const float*)d_in[2];
    const float* cls_t   = (const float*)d_in[3];
    const float* pos     = (const float*)d_in[4];
    const float* w_qkv   = (const float*)d_in[5];
    const float* b_qkv   = (const float*)d_in[6];
    const float* w_out   = (const float*)d_in[7];
    const float* b_out   = (const float*)d_in[8];
    const float* ln1w    = (const float*)d_in[9];
    const float* ln1b    = (const float*)d_in[10];
    const float* w_fc1   = (const float*)d_in[11];
    const float* b_fc1   = (const float*)d_in[12];
    const float* w_fc2   = (const float*)d_in[13];
    const float* b_fc2   = (const float*)d_in[14];
    const float* ln2w    = (const float*)d_in[15];
    const float* ln2b    = (const float*)d_in[16];

    char* ws = (char*)d_ws;
    hb* wPatch = (hb*)(ws + OFF_WPATCH);
    hb* wQKV   = (hb*)(ws + OFF_WQKV);
    hb* wOut   = (hb*)(ws + OFF_WOUT);
    hb* wFc1   = (hb*)(ws + OFF_WFC1);
    hb* wFc2   = (hb*)(ws + OFF_WFC2);
    hb* x_bf   = (hb*)(ws + OFF_XBF);
    hb* ctx    = (hb*)(ws + OFF_CTX);
    hb* Xp     = (hb*)(ws + OFF_BIG);
    hb* qkv    = (hb*)(ws + OFF_BIG);
    hb* hmid   = (hb*)(ws + OFF_BIG);
    float* x_f = (float*)(ws + OFF_XF);
    float* h1  = (float*)(ws + OFF_H1);

    // weights: patch_w row-major bf16 (LDS-staged GEMM); the rest fragment-swizzled
    cvt_bf16_kernel<<<dim3((512 * 768 + 255) / 256), dim3(256), 0, stream>>>(patch_w, wPatch, 512 * 768);
    wsw_kernel<<<dim3(384, 6), dim3(256), 0, stream>>>(w_qkv, wQKV, 512, 1536);
    wsw_kernel<<<dim3(128, 6), dim3(256), 0, stream>>>(w_out, wOut, 512, 512);
    wsw_kernel<<<dim3(512, 6), dim3(256), 0, stream>>>(w_fc1, wFc1, 512, 2048);
    wsw_kernel<<<dim3(512, 6), dim3(256), 0, stream>>>(w_fc2, wFc2, 2048, 512);

    patchify_kernel<<<dim3((PROWS * 768 + 255) / 256), dim3(256), 0, stream>>>(img, Xp);
    gemm_pe<<<dim3(4, 98), dim3(256), 0, stream>>>(Xp, wPatch, patch_b, 768, 512, x_bf, x_f, pos);
    cls_init_kernel<<<dim3(128), dim3(256), 0, stream>>>(cls_t, pos, x_f, x_bf);
    zero_pads_kernel<<<dim3(128), dim3(256), 0, stream>>>(x_f, x_bf, ctx);

    for (int i = 0; i < N_DEPTH; ++i) {
        gemm_sw<512, 0><<<dim3(12, 99), dim3(256), 0, stream>>>(x_bf, wQKV + (size_t)i * 1536 * 512,
                                                                b_qkv + i * 1536, 1536, qkv, nullptr, nullptr);
        attn_kernel<<<dim3(512), dim3(256), 0, stream>>>(qkv, ctx);
        gemm_sw<512, 2><<<dim3(4, 99), dim3(256), 0, stream>>>(ctx, wOut + (size_t)i * 512 * 512,
                                                               b_out + i * 512, 512, nullptr, h1, x_f);
        ln_kernel<<<dim3(3152), dim3(256), 0, stream>>>(h1, ln1w + i * 512, ln1b + i * 512, x_f, x_bf, ROWS);
        gemm_sw<512, 1><<<dim3(16, 99), dim3(256), 0, stream>>>(x_bf, wFc1 + (size_t)i * 2048 * 512,
                                                                b_fc1 + i * 2048, 2048, hmid, nullptr, nullptr);
        gemm_sw<2048, 2><<<dim3(4, 99), dim3(256), 0, stream>>>(hmid, wFc2 + (size_t)i * 512 * 2048,
                                                                b_fc2 + i * 512, 512, nullptr, h1, x_f);
        ln_kernel<<<dim3(3152), dim3(256), 0, stream>>>(h1, ln2w + i * 512, ln2b + i * 512, x_f, x_bf, ROWS);
    }

    extract_cls_kernel<<<dim3(128), dim3(256), 0, stream>>>(x_f, (float*)d_out);
}